// Round 1
// 366.131 us; speedup vs baseline: 1.4297x; 1.4297x over previous
//
#include <hip/hip_runtime.h>
#include <hip/hip_bf16.h>
#include <cmath>

// SparseAttentionBlock: B=2, L=4096, D=512, H=8, dh=64
// Inputs/outputs fp32; internal GEMM pipeline bf16; residual spine fp32.

#define L_SEQ 4096
#define D_MODEL 512
#define N_HEADS 8
#define D_HEAD 64
#define QKV_LD 1536

typedef __attribute__((ext_vector_type(8))) short bf16x8;
typedef __attribute__((ext_vector_type(4))) float f32x4;

__device__ __forceinline__ __hip_bfloat16 f2bf(float v) { return __float2bfloat16(v); }

__device__ __forceinline__ void gl_lds16(const __hip_bfloat16* g, __hip_bfloat16* l) {
  __builtin_amdgcn_global_load_lds((__attribute__((address_space(1))) void*)g,
                                   (__attribute__((address_space(3))) void*)l, 16, 0, 0);
}

// ---------------- fp32 -> bf16 convert (weights) ----------------
__global__ __launch_bounds__(256) void cvt_kernel(const float* __restrict__ src,
                                                  __hip_bfloat16* __restrict__ dst, int n4) {
  const int i = blockIdx.x * 256 + threadIdx.x;
  if (i < n4) {
    const float4 v = ((const float4*)src)[i];
    dst[4 * i + 0] = f2bf(v.x);
    dst[4 * i + 1] = f2bf(v.y);
    dst[4 * i + 2] = f2bf(v.z);
    dst[4 * i + 3] = f2bf(v.w);
  }
}

// ---------------- LayerNorm: fp32 in -> bf16 out ----------------
__global__ __launch_bounds__(256) void ln_kernel(const float* __restrict__ x,
                                                 const float* __restrict__ g,
                                                 const float* __restrict__ b,
                                                 __hip_bfloat16* __restrict__ out) {
  const int row = blockIdx.x;
  const int t = threadIdx.x;
  const float* xr = x + (size_t)row * D_MODEL;
  float v0 = xr[t];
  float v1 = xr[t + 256];
  float s = v0 + v1;
  float qq = v0 * v0 + v1 * v1;
  for (int off = 32; off > 0; off >>= 1) {
    s += __shfl_xor(s, off);
    qq += __shfl_xor(qq, off);
  }
  __shared__ float red[8];
  const int wid = t >> 6;
  if ((t & 63) == 0) { red[wid] = s; red[4 + wid] = qq; }
  __syncthreads();
  s = red[0] + red[1] + red[2] + red[3];
  qq = red[4] + red[5] + red[6] + red[7];
  const float mu = s * (1.0f / 512.0f);
  const float var = fmaxf(qq * (1.0f / 512.0f) - mu * mu, 0.0f);
  const float rstd = rsqrtf(var + 1e-5f);
  __hip_bfloat16* orow = out + (size_t)row * D_MODEL;
  orow[t] = f2bf((v0 - mu) * rstd * g[t] + b[t]);
  orow[t + 256] = f2bf((v1 - mu) * rstd * g[t + 256] + b[t + 256]);
}

// ---------------- V transpose: qkv V-region -> vt[b,h,dh,L] ----------------
__global__ __launch_bounds__(256) void vtrans_kernel(const __hip_bfloat16* __restrict__ qkv,
                                                     __hip_bfloat16* __restrict__ vt) {
  const int gid = blockIdx.x * 256 + threadIdx.x;  // 2*64*4096 threads exactly
  const int l = gid & 4095;
  const int bg = gid >> 12;
  const int b = bg >> 6, g = bg & 63;
  const int h = g >> 3, dg = (g & 7) * 8;
  const __hip_bfloat16* src = qkv + (size_t)(b * L_SEQ + l) * QKV_LD + 1024 + h * 64 + dg;
  bf16x8 v = *(const bf16x8*)src;
  const size_t dbase = (size_t)((b * 8 + h) * 64 + dg) * L_SEQ + l;
  for (int j = 0; j < 8; j++)
    vt[dbase + (size_t)j * L_SEQ] = ((const __hip_bfloat16*)&v)[j];  // coalesced over l
}

// ---------------- GEMM: C[M,N] = A[M,K] @ B[N,K]^T, bf16 in, fp32 accum ----------------
// EPI 0: store bf16   1: += aux(fp32), store fp32   2: silu, store bf16   3: += aux(fp32), store fp32
template <int EPI>
__global__ __launch_bounds__(256) void gemm_kernel(const __hip_bfloat16* __restrict__ A,
                                                   const __hip_bfloat16* __restrict__ B,
                                                   int M, int N, int K,
                                                   const float* __restrict__ aux,
                                                   void* __restrict__ C) {
  __shared__ __align__(16) __hip_bfloat16 As[128 * 32];
  __shared__ __align__(16) __hip_bfloat16 Bs[128 * 32];
  const int tid = threadIdx.x;
  const int lane = tid & 63, w = tid >> 6;
  const int m0 = blockIdx.y * 128, n0 = blockIdx.x * 128;
  const int wm = (w >> 1) * 64, wn = (w & 1) * 64;
  const int r = lane & 15, q = lane >> 4;

  f32x4 acc[4][4];
  const f32x4 zz = {0.f, 0.f, 0.f, 0.f};
  for (int i = 0; i < 4; i++)
    for (int j = 0; j < 4; j++) acc[i][j] = zz;

  for (int k0 = 0; k0 < K; k0 += 32) {
    for (int i = 0; i < 2; i++) {
      const int c = i * 256 + tid;
      const int row = c >> 2, kb = (c & 3) * 8;
      gl_lds16(A + (size_t)(m0 + row) * K + (k0 + kb), As + c * 8);
      gl_lds16(B + (size_t)(n0 + row) * K + (k0 + kb), Bs + c * 8);
    }
    __syncthreads();
    bf16x8 af[4], bfr[4];
    for (int mi = 0; mi < 4; mi++)
      af[mi] = *(const bf16x8*)(As + (wm + mi * 16 + r) * 32 + q * 8);
    for (int ni = 0; ni < 4; ni++)
      bfr[ni] = *(const bf16x8*)(Bs + (wn + ni * 16 + r) * 32 + q * 8);
    for (int mi = 0; mi < 4; mi++)
      for (int ni = 0; ni < 4; ni++)
        acc[mi][ni] = __builtin_amdgcn_mfma_f32_16x16x32_bf16(af[mi], bfr[ni], acc[mi][ni], 0, 0, 0);
    __syncthreads();
  }

  for (int mi = 0; mi < 4; mi++)
    for (int ni = 0; ni < 4; ni++)
      for (int j = 0; j < 4; j++) {
        const int gm = m0 + wm + mi * 16 + q * 4 + j;
        const int gn = n0 + wn + ni * 16 + r;
        float v = acc[mi][ni][j];
        const size_t idx = (size_t)gm * N + gn;
        if (EPI == 0) {
          ((__hip_bfloat16*)C)[idx] = f2bf(v);
        } else if (EPI == 1) {
          ((float*)C)[idx] = v + aux[idx];
        } else if (EPI == 2) {
          v = v / (1.0f + expf(-v));
          ((__hip_bfloat16*)C)[idx] = f2bf(v);
        } else {
          ((float*)C)[idx] = v + aux[idx];
        }
      }
}

// ---------------- Flash attention with block-shared LDS K/V staging ----------------
// KVBLK=64. K tile: 64 keys x 64 dh (8 KB). V tile: 64 dh x 64 keys (8 KB), both
// double-buffered. global_load_lds writes linearly, so the 16B chunk index within each
// 128B row is XOR-swizzled on the GLOBAL source (chunk ^= row&7) and the same XOR is
// applied on the ds_read side -> bank-conflict-free reads (2 lanes/bank).
__device__ __forceinline__ void stage_kv(int w, int lane, int key0,
                                         const __hip_bfloat16* __restrict__ Kg,
                                         const __hip_bfloat16* __restrict__ Vg,
                                         __hip_bfloat16* Ks, __hip_bfloat16* Vs) {
  const int row_in = lane >> 3;        // 0..7
  const int cs = (lane & 7) ^ row_in;  // swizzled 16B-chunk index
#pragma unroll
  for (int ii = 0; ii < 2; ii++) {
    const int i = w * 2 + ii;          // instruction 0..7 across the 4 waves
    const int row = i * 8 + row_in;    // 0..63 (K: key index, V: dh index)
    gl_lds16(Kg + (size_t)(key0 + row) * QKV_LD + cs * 8, Ks + i * 512 + lane * 8);
    gl_lds16(Vg + (size_t)row * L_SEQ + key0 + cs * 8, Vs + i * 512 + lane * 8);
  }
}

__device__ __forceinline__ void attn_tile(int key0, int lw0, int r, int q,
                                          const __hip_bfloat16* Ks,
                                          const __hip_bfloat16* Vs,
                                          const float* tsb, const float* mkb,
                                          float dfac, float scale2, const float* bq,
                                          const bf16x8& qf0, const bf16x8& qf1,
                                          const bf16x8& onesf,
                                          __hip_bfloat16* Pw,
                                          f32x4* o, f32x4& ls, float* m_r) {
  const int r7 = r & 7;
  const f32x4 zz = {0.f, 0.f, 0.f, 0.f};
  float bk[4], mk[4];
#pragma unroll
  for (int hc = 0; hc < 4; hc++) {
    const int col = key0 + hc * 16 + r;
    bk[hc] = dfac * tsb[col];
    mk[hc] = mkb[col];
  }
  f32x4 s[4];
#pragma unroll
  for (int hc = 0; hc < 4; hc++) {
    const __hip_bfloat16* kr = Ks + (hc * 16 + r) * 64;
    bf16x8 k0 = *(const bf16x8*)(kr + ((q ^ r7) * 8));
    bf16x8 k1 = *(const bf16x8*)(kr + (((q + 4) ^ r7) * 8));
    f32x4 a = zz;
    a = __builtin_amdgcn_mfma_f32_16x16x32_bf16(qf0, k0, a, 0, 0, 0);
    a = __builtin_amdgcn_mfma_f32_16x16x32_bf16(qf1, k1, a, 0, 0, 0);
    s[hc] = a;
  }
#pragma unroll
  for (int j = 0; j < 4; j++) {
    const int rowg = lw0 + q * 4 + j;
    float lg[4];
    float best = -INFINITY;
#pragma unroll
    for (int hc = 0; hc < 4; hc++) {
      const int col = key0 + hc * 16 + r;
      float v = fmaf(s[hc][j], scale2, bk[hc] - bq[j]);  // log2-domain score
      const bool valid = (col <= rowg) && (mk[hc] != 0.f);
      v = valid ? v : -INFINITY;
      lg[hc] = v;
      best = fmaxf(best, v);
    }
    best = fmaxf(best, __shfl_xor(best, 1));
    best = fmaxf(best, __shfl_xor(best, 2));
    best = fmaxf(best, __shfl_xor(best, 4));
    best = fmaxf(best, __shfl_xor(best, 8));
    float mnew = fmaxf(m_r[j], best);
    if (mnew == -INFINITY) mnew = 0.f;  // fully-masked guard
    const float alpha = exp2f(m_r[j] - mnew);
    m_r[j] = mnew;
#pragma unroll
    for (int hc = 0; hc < 4; hc++)
      Pw[(q * 4 + j) * 72 + hc * 16 + r] = f2bf(exp2f(lg[hc] - mnew));
    ls[j] *= alpha;
#pragma unroll
    for (int c = 0; c < 4; c++) o[c][j] *= alpha;
  }
  // O += P V ; rowsum via ones fragment (wave-private LDS: no __syncthreads needed)
#pragma unroll
  for (int kc = 0; kc < 2; kc++) {
    bf16x8 pf = *(const bf16x8*)(Pw + r * 72 + kc * 32 + q * 8);
#pragma unroll
    for (int c = 0; c < 4; c++) {
      const __hip_bfloat16* vr = Vs + (c * 16 + r) * 64 + (((kc * 4 + q) ^ r7) * 8);
      bf16x8 vf = *(const bf16x8*)vr;
      o[c] = __builtin_amdgcn_mfma_f32_16x16x32_bf16(pf, vf, o[c], 0, 0, 0);
    }
    ls = __builtin_amdgcn_mfma_f32_16x16x32_bf16(pf, onesf, ls, 0, 0, 0);
  }
}

// grid: 1024 blocks (heavy-first); 4 waves/block share LDS-staged K/V; wave owns 16 q-rows.
__global__ __launch_bounds__(256, 3) void attn_kernel(const __hip_bfloat16* __restrict__ qkv,
                                                      const __hip_bfloat16* __restrict__ vt,
                                                      const float* __restrict__ ts,
                                                      const float* __restrict__ mask,
                                                      const float* __restrict__ decay_rate,
                                                      __hip_bfloat16* __restrict__ out) {
  const int blk = blockIdx.x;
  const int qi = 63 - (blk >> 4);  // heavy diagonals first
  const int bh = blk & 15;
  const int b = bh >> 3, h = bh & 7;
  const int l0 = qi * 64;
  const int tid = threadIdx.x, lane = tid & 63, w = tid >> 6;
  const int lw0 = l0 + w * 16;
  const int r = lane & 15, q = lane >> 4;

  __shared__ __align__(16) __hip_bfloat16 Ksm[2][64 * 64];
  __shared__ __align__(16) __hip_bfloat16 Vsm[2][64 * 64];
  __shared__ __align__(16) __hip_bfloat16 Pl[4][16 * 72];  // wave-private, stride-72 pad
  __hip_bfloat16* Pw = Pl[w];

  const float LOG2E = 1.4426950408889634f;
  const float decay = log1pf(expf(decay_rate[h]));
  const float dfac = decay * (1.0f / 24.0f) * LOG2E;
  const float scale2 = 0.125f * LOG2E;

  const __hip_bfloat16* Kg = qkv + (size_t)b * L_SEQ * QKV_LD + 512 + h * 64;
  const __hip_bfloat16* Vg = vt + (size_t)bh * 64 * L_SEQ;
  const float* tsb = ts + b * L_SEQ;
  const float* mkb = mask + b * L_SEQ;

  // prologue: stage tile 0 while loading Q fragments
  stage_kv(w, lane, l0 * 0 + 0, Kg, Vg, Ksm[0], Vsm[0]);

  bf16x8 qf0, qf1;
  {
    const __hip_bfloat16* qrow = qkv + (size_t)(b * L_SEQ + lw0 + r) * QKV_LD + h * 64 + q * 8;
    qf0 = *(const bf16x8*)qrow;
    qf1 = *(const bf16x8*)(qrow + 32);
  }
  float bq[4];
  for (int j = 0; j < 4; j++) bq[j] = dfac * ts[b * L_SEQ + lw0 + q * 4 + j];

  const f32x4 zz = {0.f, 0.f, 0.f, 0.f};
  f32x4 o[4];
  for (int c = 0; c < 4; c++) o[c] = zz;
  f32x4 ls = zz;
  float m_r[4];
  for (int j = 0; j < 4; j++) m_r[j] = -INFINITY;

  bf16x8 onesf;
  for (int i = 0; i < 8; i++) ((short*)&onesf)[i] = (short)0x3F80;  // bf16 1.0

  const int ntiles = qi + 1;  // 64-key tiles, keys [0, l0+64)
  __syncthreads();            // drains prologue stage (vmcnt) + all waves ready
  for (int t = 0; t < ntiles; t++) {
    const int cur = t & 1;
    if (t + 1 < ntiles)
      stage_kv(w, lane, (t + 1) << 6, Kg, Vg, Ksm[cur ^ 1], Vsm[cur ^ 1]);
    attn_tile(t << 6, lw0, r, q, Ksm[cur], Vsm[cur], tsb, mkb, dfac, scale2, bq,
              qf0, qf1, onesf, Pw, o, ls, m_r);
    __syncthreads();  // waves done reading cur; next-tile loads drained
  }

  float inv[4];
  for (int j = 0; j < 4; j++) inv[j] = 1.0f / ls[j];
  for (int c = 0; c < 4; c++)
    for (int j = 0; j < 4; j++) {
      const int rowg = lw0 + q * 4 + j;
      out[(size_t)(b * L_SEQ + rowg) * D_MODEL + h * 64 + c * 16 + r] = f2bf(o[c][j] * inv[j]);
    }
}

// ---------------- Launch ----------------
extern "C" void kernel_launch(void* const* d_in, const int* in_sizes, int n_in,
                              void* d_out, int out_size, void* d_ws, size_t ws_size,
                              hipStream_t stream) {
  const float* x = (const float*)d_in[0];
  const float* ts = (const float*)d_in[1];
  const float* mask = (const float*)d_in[2];
  const float* ln1_g = (const float*)d_in[3];
  const float* ln1_b = (const float*)d_in[4];
  const float* w_qkv = (const float*)d_in[5];
  const float* w_out = (const float*)d_in[6];
  const float* decay = (const float*)d_in[7];
  const float* ln2_g = (const float*)d_in[8];
  const float* ln2_b = (const float*)d_in[9];
  const float* w_ff1 = (const float*)d_in[10];
  const float* w_ff2 = (const float*)d_in[11];

  char* ws = (char*)d_ws;
  // layout (bytes):
  //   [0, 6M)    weights bf16
  //   [6M, 14M)  xn (dead after gemm0) -> vt overlays
  //   [14M, 38M) qkv (dead after attn)
  //   [38M, 46M) attnout -> h
  //   [46M, 62M) x2 (fp32)
  //   ff1out overlays [6M, 38M)
  __hip_bfloat16* wqkv_b = (__hip_bfloat16*)(ws + 0);
  __hip_bfloat16* wout_b = (__hip_bfloat16*)(ws + 1572864);
  __hip_bfloat16* wff1_b = (__hip_bfloat16*)(ws + 2097152);
  __hip_bfloat16* wff2_b = (__hip_bfloat16*)(ws + 4194304);
  __hip_bfloat16* xn = (__hip_bfloat16*)(ws + 6291456);
  __hip_bfloat16* vt = (__hip_bfloat16*)(ws + 6291456);
  __hip_bfloat16* qkv = (__hip_bfloat16*)(ws + 14680064);
  __hip_bfloat16* attnout = (__hip_bfloat16*)(ws + 39845888);
  __hip_bfloat16* h = attnout;
  __hip_bfloat16* ff1out = (__hip_bfloat16*)(ws + 6291456);
  float* x2 = (float*)(ws + 48234496);
  float* out = (float*)d_out;

  const int M = 2 * L_SEQ;  // 8192

  cvt_kernel<<<dim3(768), dim3(256), 0, stream>>>(w_qkv, wqkv_b, 196608);
  cvt_kernel<<<dim3(256), dim3(256), 0, stream>>>(w_out, wout_b, 65536);
  cvt_kernel<<<dim3(1024), dim3(256), 0, stream>>>(w_ff1, wff1_b, 262144);
  cvt_kernel<<<dim3(1024), dim3(256), 0, stream>>>(w_ff2, wff2_b, 262144);

  ln_kernel<<<dim3(M), dim3(256), 0, stream>>>(x, ln1_g, ln1_b, xn);
  gemm_kernel<0><<<dim3(12, 64), dim3(256), 0, stream>>>(xn, wqkv_b, M, 1536, 512, nullptr, qkv);
  vtrans_kernel<<<dim3(2048), dim3(256), 0, stream>>>(qkv, vt);
  attn_kernel<<<dim3(1024), dim3(256), 0, stream>>>(qkv, vt, ts, mask, decay, attnout);
  gemm_kernel<1><<<dim3(4, 64), dim3(256), 0, stream>>>(attnout, wout_b, M, 512, 512, x, x2);
  ln_kernel<<<dim3(M), dim3(256), 0, stream>>>(x2, ln2_g, ln2_b, h);
  gemm_kernel<2><<<dim3(16, 64), dim3(256), 0, stream>>>(h, wff1_b, M, 2048, 512, nullptr, ff1out);
  gemm_kernel<3><<<dim3(4, 64), dim3(256), 0, stream>>>(ff1out, wff2_b, M, 512, 2048, x2, out);
}

// Round 2
// 351.166 us; speedup vs baseline: 1.4907x; 1.0426x over previous
//
#include <hip/hip_runtime.h>
#include <hip/hip_bf16.h>
#include <cmath>

// SparseAttentionBlock: B=2, L=4096, D=512, H=8, dh=64
// Inputs/outputs fp32; internal GEMM pipeline bf16; residual spine fp32.

#define L_SEQ 4096
#define D_MODEL 512
#define N_HEADS 8
#define D_HEAD 64
#define QKV_LD 1536

typedef __attribute__((ext_vector_type(8))) short bf16x8;
typedef __attribute__((ext_vector_type(4))) float f32x4;

__device__ __forceinline__ __hip_bfloat16 f2bf(float v) { return __float2bfloat16(v); }

__device__ __forceinline__ void gl_lds16(const __hip_bfloat16* g, __hip_bfloat16* l) {
  __builtin_amdgcn_global_load_lds((__attribute__((address_space(1))) void*)g,
                                   (__attribute__((address_space(3))) void*)l, 16, 0, 0);
}

// ---------------- fp32 -> bf16 convert: all 4 weight tensors in ONE launch ----------------
__global__ __launch_bounds__(256) void cvt4_kernel(const float* __restrict__ s0, __hip_bfloat16* __restrict__ d0,
                                                   const float* __restrict__ s1, __hip_bfloat16* __restrict__ d1,
                                                   const float* __restrict__ s2, __hip_bfloat16* __restrict__ d2,
                                                   const float* __restrict__ s3, __hip_bfloat16* __restrict__ d3) {
  const int i = blockIdx.x * 256 + threadIdx.x;  // grid 3072 -> 786432 float4s total
  const float* s;
  __hip_bfloat16* d;
  int off;
  if (i < 196608) { s = s0; d = d0; off = i; }
  else if (i < 262144) { s = s1; d = d1; off = i - 196608; }
  else if (i < 524288) { s = s2; d = d2; off = i - 262144; }
  else { s = s3; d = d3; off = i - 524288; }
  const float4 v = ((const float4*)s)[off];
  d[4 * off + 0] = f2bf(v.x);
  d[4 * off + 1] = f2bf(v.y);
  d[4 * off + 2] = f2bf(v.z);
  d[4 * off + 3] = f2bf(v.w);
}

// ---------------- LayerNorm: fp32 in -> bf16 out ----------------
__global__ __launch_bounds__(256) void ln_kernel(const float* __restrict__ x,
                                                 const float* __restrict__ g,
                                                 const float* __restrict__ b,
                                                 __hip_bfloat16* __restrict__ out) {
  const int row = blockIdx.x;
  const int t = threadIdx.x;
  const float* xr = x + (size_t)row * D_MODEL;
  float v0 = xr[t];
  float v1 = xr[t + 256];
  float s = v0 + v1;
  float qq = v0 * v0 + v1 * v1;
  for (int off = 32; off > 0; off >>= 1) {
    s += __shfl_xor(s, off);
    qq += __shfl_xor(qq, off);
  }
  __shared__ float red[8];
  const int wid = t >> 6;
  if ((t & 63) == 0) { red[wid] = s; red[4 + wid] = qq; }
  __syncthreads();
  s = red[0] + red[1] + red[2] + red[3];
  qq = red[4] + red[5] + red[6] + red[7];
  const float mu = s * (1.0f / 512.0f);
  const float var = fmaxf(qq * (1.0f / 512.0f) - mu * mu, 0.0f);
  const float rstd = rsqrtf(var + 1e-5f);
  __hip_bfloat16* orow = out + (size_t)row * D_MODEL;
  orow[t] = f2bf((v0 - mu) * rstd * g[t] + b[t]);
  orow[t + 256] = f2bf((v1 - mu) * rstd * g[t + 256] + b[t + 256]);
}

// ---------------- V transpose: qkv V-region -> vt[b,h,dh,L] ----------------
__global__ __launch_bounds__(256) void vtrans_kernel(const __hip_bfloat16* __restrict__ qkv,
                                                     __hip_bfloat16* __restrict__ vt) {
  const int gid = blockIdx.x * 256 + threadIdx.x;  // 2*64*4096 threads exactly
  const int l = gid & 4095;
  const int bg = gid >> 12;
  const int b = bg >> 6, g = bg & 63;
  const int h = g >> 3, dg = (g & 7) * 8;
  const __hip_bfloat16* src = qkv + (size_t)(b * L_SEQ + l) * QKV_LD + 1024 + h * 64 + dg;
  bf16x8 v = *(const bf16x8*)src;
  const size_t dbase = (size_t)((b * 8 + h) * 64 + dg) * L_SEQ + l;
  for (int j = 0; j < 8; j++)
    vt[dbase + (size_t)j * L_SEQ] = ((const __hip_bfloat16*)&v)[j];  // coalesced over l
}

// ---------------- GEMM: C[M,N] = A[M,K] @ B[N,K]^T, bf16 in, fp32 accum ----------------
// Double-buffered LDS + counted vmcnt (T4): no vmcnt(0) drain in the K-loop.
// EPI 0: store bf16   1: += aux(fp32), store fp32   2: silu, store bf16   3: += aux(fp32), store fp32
template <int EPI>
__global__ __launch_bounds__(256) void gemm_kernel(const __hip_bfloat16* __restrict__ A,
                                                   const __hip_bfloat16* __restrict__ B,
                                                   int M, int N, int K,
                                                   const float* __restrict__ aux,
                                                   void* __restrict__ C) {
  __shared__ __align__(16) __hip_bfloat16 As[2][128 * 32];
  __shared__ __align__(16) __hip_bfloat16 Bs[2][128 * 32];
  const int tid = threadIdx.x;
  const int lane = tid & 63, w = tid >> 6;
  const int m0 = blockIdx.y * 128, n0 = blockIdx.x * 128;
  const int wm = (w >> 1) * 64, wn = (w & 1) * 64;
  const int r = lane & 15, q = lane >> 4;

  f32x4 acc[4][4];
  const f32x4 zz = {0.f, 0.f, 0.f, 0.f};
  for (int i = 0; i < 4; i++)
    for (int j = 0; j < 4; j++) acc[i][j] = zz;

  const int c0 = tid, c1 = 256 + tid;
  const int row0 = c0 >> 2, kb0 = (c0 & 3) * 8;
  const int row1 = c1 >> 2, kb1 = (c1 & 3) * 8;

#define GEMM_STAGE(k0, buf)                                                     \
  do {                                                                          \
    gl_lds16(A + (size_t)(m0 + row0) * K + ((k0) + kb0), &As[buf][c0 * 8]);     \
    gl_lds16(B + (size_t)(n0 + row0) * K + ((k0) + kb0), &Bs[buf][c0 * 8]);     \
    gl_lds16(A + (size_t)(m0 + row1) * K + ((k0) + kb1), &As[buf][c1 * 8]);     \
    gl_lds16(B + (size_t)(n0 + row1) * K + ((k0) + kb1), &Bs[buf][c1 * 8]);     \
  } while (0)

  GEMM_STAGE(0, 0);
  const int niter = K >> 5;
  for (int it = 0; it < niter; it++) {
    const int cur = it & 1;
    if (it + 1 < niter) {
      GEMM_STAGE((it + 1) << 5, cur ^ 1);
      asm volatile("s_waitcnt vmcnt(4)" ::: "memory");  // own iter-it loads retired
    } else {
      asm volatile("s_waitcnt vmcnt(0)" ::: "memory");
    }
    __builtin_amdgcn_s_barrier();  // all waves' iter-it stage complete
    bf16x8 af[4], bfr[4];
    for (int mi = 0; mi < 4; mi++)
      af[mi] = *(const bf16x8*)(&As[cur][(wm + mi * 16 + r) * 32 + q * 8]);
    for (int ni = 0; ni < 4; ni++)
      bfr[ni] = *(const bf16x8*)(&Bs[cur][(wn + ni * 16 + r) * 32 + q * 8]);
    for (int mi = 0; mi < 4; mi++)
      for (int ni = 0; ni < 4; ni++)
        acc[mi][ni] = __builtin_amdgcn_mfma_f32_16x16x32_bf16(af[mi], bfr[ni], acc[mi][ni], 0, 0, 0);
    __builtin_amdgcn_s_barrier();  // reads of buf[cur] done before it+1 overwrites it
  }
#undef GEMM_STAGE

  for (int mi = 0; mi < 4; mi++)
    for (int ni = 0; ni < 4; ni++)
      for (int j = 0; j < 4; j++) {
        const int gm = m0 + wm + mi * 16 + q * 4 + j;
        const int gn = n0 + wn + ni * 16 + r;
        float v = acc[mi][ni][j];
        const size_t idx = (size_t)gm * N + gn;
        if (EPI == 0) {
          ((__hip_bfloat16*)C)[idx] = f2bf(v);
        } else if (EPI == 1) {
          ((float*)C)[idx] = v + aux[idx];
        } else if (EPI == 2) {
          v = v / (1.0f + expf(-v));
          ((__hip_bfloat16*)C)[idx] = f2bf(v);
        } else {
          ((float*)C)[idx] = v + aux[idx];
        }
      }
}

// ---------------- Flash attention with block-shared LDS K/V staging ----------------
// KVBLK=64, double-buffered, counted-vmcnt barriers (no per-tile vmcnt(0) drain).
// global_load_lds writes linearly, so the 16B chunk index within each 128B row is
// XOR-swizzled on the GLOBAL source (chunk ^= row&7) and the same XOR is applied on
// the ds_read side -> bank-conflict-free reads.
__device__ __forceinline__ void stage_kv(int w, int lane, int key0,
                                         const __hip_bfloat16* __restrict__ Kg,
                                         const __hip_bfloat16* __restrict__ Vg,
                                         __hip_bfloat16* Ks, __hip_bfloat16* Vs) {
  const int row_in = lane >> 3;        // 0..7
  const int cs = (lane & 7) ^ row_in;  // swizzled 16B-chunk index
#pragma unroll
  for (int ii = 0; ii < 2; ii++) {
    const int i = w * 2 + ii;          // instruction 0..7 across the 4 waves
    const int row = i * 8 + row_in;    // 0..63 (K: key index, V: dh index)
    gl_lds16(Kg + (size_t)(key0 + row) * QKV_LD + cs * 8, Ks + i * 512 + lane * 8);
    gl_lds16(Vg + (size_t)row * L_SEQ + key0 + cs * 8, Vs + i * 512 + lane * 8);
  }
}

// CAUSAL: per-element col<=row test (diagonal tile only). Mask is folded into the
// per-column bias bk[] (valid-path arithmetic identical to the reference).
template <bool CAUSAL>
__device__ __forceinline__ void attn_tile(int key0, int lw0, int r, int q,
                                          const __hip_bfloat16* Ks,
                                          const __hip_bfloat16* Vs,
                                          const float* tsb, const float* mkb,
                                          float dfac, float scale2, const float* bq,
                                          const bf16x8& qf0, const bf16x8& qf1,
                                          const bf16x8& onesf,
                                          __hip_bfloat16* Pw,
                                          f32x4* o, f32x4& ls, float* m_r) {
  const int r7 = r & 7;
  const f32x4 zz = {0.f, 0.f, 0.f, 0.f};
  float bk[4];
#pragma unroll
  for (int hc = 0; hc < 4; hc++) {
    const int col = key0 + hc * 16 + r;
    bk[hc] = dfac * tsb[col] + (mkb[col] != 0.f ? 0.f : -1e30f);
  }
  f32x4 s[4];
  __builtin_amdgcn_s_setprio(1);
#pragma unroll
  for (int hc = 0; hc < 4; hc++) {
    const __hip_bfloat16* kr = Ks + (hc * 16 + r) * 64;
    bf16x8 k0 = *(const bf16x8*)(kr + ((q ^ r7) * 8));
    bf16x8 k1 = *(const bf16x8*)(kr + (((q + 4) ^ r7) * 8));
    f32x4 a = zz;
    a = __builtin_amdgcn_mfma_f32_16x16x32_bf16(qf0, k0, a, 0, 0, 0);
    a = __builtin_amdgcn_mfma_f32_16x16x32_bf16(qf1, k1, a, 0, 0, 0);
    s[hc] = a;
  }
  __builtin_amdgcn_s_setprio(0);
#pragma unroll
  for (int j = 0; j < 4; j++) {
    const int rowg = lw0 + q * 4 + j;
    float lg[4];
    float best = -INFINITY;
#pragma unroll
    for (int hc = 0; hc < 4; hc++) {
      float v = fmaf(s[hc][j], scale2, bk[hc] - bq[j]);  // log2-domain score
      if (CAUSAL) {
        const int col = key0 + hc * 16 + r;
        v = (col <= rowg) ? v : -INFINITY;
      }
      lg[hc] = v;
      best = fmaxf(best, v);
    }
    best = fmaxf(best, __shfl_xor(best, 1));
    best = fmaxf(best, __shfl_xor(best, 2));
    best = fmaxf(best, __shfl_xor(best, 4));
    best = fmaxf(best, __shfl_xor(best, 8));
    float mnew = fmaxf(m_r[j], best);
    if (mnew == -INFINITY) mnew = 0.f;  // fully-masked guard
    const float alpha = exp2f(m_r[j] - mnew);
    m_r[j] = mnew;
#pragma unroll
    for (int hc = 0; hc < 4; hc++)
      Pw[(q * 4 + j) * 72 + hc * 16 + r] = f2bf(exp2f(lg[hc] - mnew));
    ls[j] *= alpha;
#pragma unroll
    for (int c = 0; c < 4; c++) o[c][j] *= alpha;
  }
  // O += P V ; rowsum via ones fragment (wave-private LDS: no cross-wave sync needed)
  __builtin_amdgcn_s_setprio(1);
#pragma unroll
  for (int kc = 0; kc < 2; kc++) {
    bf16x8 pf = *(const bf16x8*)(Pw + r * 72 + kc * 32 + q * 8);
#pragma unroll
    for (int c = 0; c < 4; c++) {
      const __hip_bfloat16* vr = Vs + (c * 16 + r) * 64 + (((kc * 4 + q) ^ r7) * 8);
      bf16x8 vf = *(const bf16x8*)vr;
      o[c] = __builtin_amdgcn_mfma_f32_16x16x32_bf16(pf, vf, o[c], 0, 0, 0);
    }
    ls = __builtin_amdgcn_mfma_f32_16x16x32_bf16(pf, onesf, ls, 0, 0, 0);
  }
  __builtin_amdgcn_s_setprio(0);
}

// grid: 1024 blocks (heavy-first); 4 waves/block share LDS-staged K/V; wave owns 16 q-rows.
__global__ __launch_bounds__(256, 3) void attn_kernel(const __hip_bfloat16* __restrict__ qkv,
                                                      const __hip_bfloat16* __restrict__ vt,
                                                      const float* __restrict__ ts,
                                                      const float* __restrict__ mask,
                                                      const float* __restrict__ decay_rate,
                                                      __hip_bfloat16* __restrict__ out) {
  const int blk = blockIdx.x;
  const int qi = 63 - (blk >> 4);  // heavy diagonals first
  const int bh = blk & 15;
  const int b = bh >> 3, h = bh & 7;
  const int l0 = qi * 64;
  const int tid = threadIdx.x, lane = tid & 63, w = tid >> 6;
  const int lw0 = l0 + w * 16;
  const int r = lane & 15, q = lane >> 4;

  __shared__ __align__(16) __hip_bfloat16 Ksm[2][64 * 64];
  __shared__ __align__(16) __hip_bfloat16 Vsm[2][64 * 64];
  __shared__ __align__(16) __hip_bfloat16 Pl[4][16 * 72];  // wave-private, stride-72 pad
  __hip_bfloat16* Pw = Pl[w];

  const float LOG2E = 1.4426950408889634f;
  const float decay = log1pf(expf(decay_rate[h]));
  const float dfac = decay * (1.0f / 24.0f) * LOG2E;
  const float scale2 = 0.125f * LOG2E;

  const __hip_bfloat16* Kg = qkv + (size_t)b * L_SEQ * QKV_LD + 512 + h * 64;
  const __hip_bfloat16* Vg = vt + (size_t)bh * 64 * L_SEQ;
  const float* tsb = ts + b * L_SEQ;
  const float* mkb = mask + b * L_SEQ;

  // prologue: stage tile 0 while loading Q fragments
  stage_kv(w, lane, 0, Kg, Vg, Ksm[0], Vsm[0]);

  bf16x8 qf0, qf1;
  {
    const __hip_bfloat16* qrow = qkv + (size_t)(b * L_SEQ + lw0 + r) * QKV_LD + h * 64 + q * 8;
    qf0 = *(const bf16x8*)qrow;
    qf1 = *(const bf16x8*)(qrow + 32);
  }
  float bq[4];
  for (int j = 0; j < 4; j++) bq[j] = dfac * ts[b * L_SEQ + lw0 + q * 4 + j];

  const f32x4 zz = {0.f, 0.f, 0.f, 0.f};
  f32x4 o[4];
  for (int c = 0; c < 4; c++) o[c] = zz;
  f32x4 ls = zz;
  float m_r[4];
  for (int j = 0; j < 4; j++) m_r[j] = -INFINITY;

  bf16x8 onesf;
  for (int i = 0; i < 8; i++) ((short*)&onesf)[i] = (short)0x3F80;  // bf16 1.0

  const int ntiles = qi + 1;  // 64-key tiles, keys [0, l0+64); last tile is diagonal
  for (int t = 0; t < ntiles; t++) {
    const int cur = t & 1;
    if (t + 1 < ntiles) {
      stage_kv(w, lane, (t + 1) << 6, Kg, Vg, Ksm[cur ^ 1], Vsm[cur ^ 1]);
      asm volatile("s_waitcnt vmcnt(4)" ::: "memory");  // own tile-t stage retired
    } else {
      asm volatile("s_waitcnt vmcnt(0)" ::: "memory");
    }
    __builtin_amdgcn_s_barrier();  // all waves' tile-t stage complete
    if (t < ntiles - 1)
      attn_tile<false>(t << 6, lw0, r, q, Ksm[cur], Vsm[cur], tsb, mkb, dfac, scale2, bq,
                       qf0, qf1, onesf, Pw, o, ls, m_r);
    else
      attn_tile<true>(t << 6, lw0, r, q, Ksm[cur], Vsm[cur], tsb, mkb, dfac, scale2, bq,
                      qf0, qf1, onesf, Pw, o, ls, m_r);
    __builtin_amdgcn_s_barrier();  // reads of buf[cur] done before t+1 overwrites it
  }

  float inv[4];
  for (int j = 0; j < 4; j++) inv[j] = 1.0f / ls[j];
  for (int c = 0; c < 4; c++)
    for (int j = 0; j < 4; j++) {
      const int rowg = lw0 + q * 4 + j;
      out[(size_t)(b * L_SEQ + rowg) * D_MODEL + h * 64 + c * 16 + r] = f2bf(o[c][j] * inv[j]);
    }
}

// ---------------- Launch ----------------
extern "C" void kernel_launch(void* const* d_in, const int* in_sizes, int n_in,
                              void* d_out, int out_size, void* d_ws, size_t ws_size,
                              hipStream_t stream) {
  const float* x = (const float*)d_in[0];
  const float* ts = (const float*)d_in[1];
  const float* mask = (const float*)d_in[2];
  const float* ln1_g = (const float*)d_in[3];
  const float* ln1_b = (const float*)d_in[4];
  const float* w_qkv = (const float*)d_in[5];
  const float* w_out = (const float*)d_in[6];
  const float* decay = (const float*)d_in[7];
  const float* ln2_g = (const float*)d_in[8];
  const float* ln2_b = (const float*)d_in[9];
  const float* w_ff1 = (const float*)d_in[10];
  const float* w_ff2 = (const float*)d_in[11];

  char* ws = (char*)d_ws;
  // layout (bytes):
  //   [0, 6M)    weights bf16
  //   [6M, 14M)  xn (dead after gemm0) -> vt overlays
  //   [14M, 38M) qkv (dead after attn)
  //   [38M, 46M) attnout -> h
  //   [46M, 62M) x2 (fp32)
  //   ff1out overlays [6M, 38M)
  __hip_bfloat16* wqkv_b = (__hip_bfloat16*)(ws + 0);
  __hip_bfloat16* wout_b = (__hip_bfloat16*)(ws + 1572864);
  __hip_bfloat16* wff1_b = (__hip_bfloat16*)(ws + 2097152);
  __hip_bfloat16* wff2_b = (__hip_bfloat16*)(ws + 4194304);
  __hip_bfloat16* xn = (__hip_bfloat16*)(ws + 6291456);
  __hip_bfloat16* vt = (__hip_bfloat16*)(ws + 6291456);
  __hip_bfloat16* qkv = (__hip_bfloat16*)(ws + 14680064);
  __hip_bfloat16* attnout = (__hip_bfloat16*)(ws + 39845888);
  __hip_bfloat16* h = attnout;
  __hip_bfloat16* ff1out = (__hip_bfloat16*)(ws + 6291456);
  float* x2 = (float*)(ws + 48234496);
  float* out = (float*)d_out;

  const int M = 2 * L_SEQ;  // 8192

  cvt4_kernel<<<dim3(3072), dim3(256), 0, stream>>>(w_qkv, wqkv_b, w_out, wout_b,
                                                    w_ff1, wff1_b, w_ff2, wff2_b);

  ln_kernel<<<dim3(M), dim3(256), 0, stream>>>(x, ln1_g, ln1_b, xn);
  gemm_kernel<0><<<dim3(12, 64), dim3(256), 0, stream>>>(xn, wqkv_b, M, 1536, 512, nullptr, qkv);
  vtrans_kernel<<<dim3(2048), dim3(256), 0, stream>>>(qkv, vt);
  attn_kernel<<<dim3(1024), dim3(256), 0, stream>>>(qkv, vt, ts, mask, decay, attnout);
  gemm_kernel<1><<<dim3(4, 64), dim3(256), 0, stream>>>(attnout, wout_b, M, 512, 512, x, x2);
  ln_kernel<<<dim3(M), dim3(256), 0, stream>>>(x2, ln2_g, ln2_b, h);
  gemm_kernel<2><<<dim3(16, 64), dim3(256), 0, stream>>>(h, wff1_b, M, 2048, 512, nullptr, ff1out);
  gemm_kernel<3><<<dim3(4, 64), dim3(256), 0, stream>>>(ff1out, wff2_b, M, 512, 2048, x2, out);
}

// Round 4
// 307.265 us; speedup vs baseline: 1.7037x; 1.1429x over previous
//
#include <hip/hip_runtime.h>
#include <hip/hip_bf16.h>
#include <cmath>

// SparseAttentionBlock: B=2, L=4096, D=512, H=8, dh=64
// Inputs/outputs fp32; internal GEMM pipeline bf16; residual spine fp32.

#define L_SEQ 4096
#define D_MODEL 512
#define N_HEADS 8
#define D_HEAD 64
#define QKV_LD 1536

typedef __attribute__((ext_vector_type(8))) short bf16x8;
typedef __attribute__((ext_vector_type(4))) float f32x4;
typedef __attribute__((ext_vector_type(4))) unsigned u32x4;

__device__ __forceinline__ __hip_bfloat16 f2bf(float v) { return __float2bfloat16(v); }

__device__ __forceinline__ void gl_lds16(const __hip_bfloat16* g, __hip_bfloat16* l) {
  __builtin_amdgcn_global_load_lds((__attribute__((address_space(1))) void*)g,
                                   (__attribute__((address_space(3))) void*)l, 16, 0, 0);
}

// ---------------- fp32 -> bf16 convert: all 4 weight tensors in ONE launch ----------------
__global__ __launch_bounds__(256) void cvt4_kernel(const float* __restrict__ s0, __hip_bfloat16* __restrict__ d0,
                                                   const float* __restrict__ s1, __hip_bfloat16* __restrict__ d1,
                                                   const float* __restrict__ s2, __hip_bfloat16* __restrict__ d2,
                                                   const float* __restrict__ s3, __hip_bfloat16* __restrict__ d3) {
  const int i = blockIdx.x * 256 + threadIdx.x;  // grid 3072 -> 786432 float4s total
  const float* s;
  __hip_bfloat16* d;
  int off;
  if (i < 196608) { s = s0; d = d0; off = i; }
  else if (i < 262144) { s = s1; d = d1; off = i - 196608; }
  else if (i < 524288) { s = s2; d = d2; off = i - 262144; }
  else { s = s3; d = d3; off = i - 524288; }
  const float4 v = ((const float4*)s)[off];
  d[4 * off + 0] = f2bf(v.x);
  d[4 * off + 1] = f2bf(v.y);
  d[4 * off + 2] = f2bf(v.z);
  d[4 * off + 3] = f2bf(v.w);
}

// ---------------- per-(b,h) key bias: dfac_h * ts + mask fold (log2 domain) ----------------
__global__ __launch_bounds__(256) void bias_kernel(const float* __restrict__ ts,
                                                   const float* __restrict__ mask,
                                                   const float* __restrict__ decay_rate,
                                                   float* __restrict__ biasH) {
  const int idx = blockIdx.x * 256 + threadIdx.x;  // 65536 = 2*8*4096
  const int col = idx & 4095;
  const int h = (idx >> 12) & 7;
  const int b = idx >> 15;
  const float LOG2E = 1.4426950408889634f;
  const float dfac = log1pf(expf(decay_rate[h])) * (1.0f / 24.0f) * LOG2E;
  const float m = mask[b * 4096 + col];
  biasH[idx] = dfac * ts[b * 4096 + col] + (m != 0.f ? 0.f : -1e30f);
}

// ---------------- LayerNorm: fp32 in -> bf16 out ----------------
__global__ __launch_bounds__(256) void ln_kernel(const float* __restrict__ x,
                                                 const float* __restrict__ g,
                                                 const float* __restrict__ b,
                                                 __hip_bfloat16* __restrict__ out) {
  const int row = blockIdx.x;
  const int t = threadIdx.x;
  const float* xr = x + (size_t)row * D_MODEL;
  float v0 = xr[t];
  float v1 = xr[t + 256];
  float s = v0 + v1;
  float qq = v0 * v0 + v1 * v1;
  for (int off = 32; off > 0; off >>= 1) {
    s += __shfl_xor(s, off);
    qq += __shfl_xor(qq, off);
  }
  __shared__ float red[8];
  const int wid = t >> 6;
  if ((t & 63) == 0) { red[wid] = s; red[4 + wid] = qq; }
  __syncthreads();
  s = red[0] + red[1] + red[2] + red[3];
  qq = red[4] + red[5] + red[6] + red[7];
  const float mu = s * (1.0f / 512.0f);
  const float var = fmaxf(qq * (1.0f / 512.0f) - mu * mu, 0.0f);
  const float rstd = rsqrtf(var + 1e-5f);
  __hip_bfloat16* orow = out + (size_t)row * D_MODEL;
  orow[t] = f2bf((v0 - mu) * rstd * g[t] + b[t]);
  orow[t + 256] = f2bf((v1 - mu) * rstd * g[t + 256] + b[t + 256]);
}

// ---------------- V transpose: qkv V-region -> vt[b,h,dh, sigma-permuted L] ----------------
// sigma permutes key order WITHIN each 64-key tile (softmax is key-order invariant):
//   key bits [kc][a][q1][q0][j1][j0] -> slot [kc][q1][q0][a][j1][j0]
// so that after swapped QK^T each lane's own P values land in its own PV A-fragment slots.
__global__ __launch_bounds__(256) void vtrans_kernel(const __hip_bfloat16* __restrict__ qkv,
                                                     __hip_bfloat16* __restrict__ vt) {
  const int gid = blockIdx.x * 256 + threadIdx.x;  // 2*64*4096 threads exactly
  const int l = gid & 4095;
  const int bg = gid >> 12;
  const int b = bg >> 6, g = bg & 63;
  const int h = g >> 3, dg = (g & 7) * 8;
  const __hip_bfloat16* src = qkv + (size_t)(b * L_SEQ + l) * QKV_LD + 1024 + h * 64 + dg;
  bf16x8 v = *(const bf16x8*)src;
  const int kin = l & 63;
  const int sl = (kin & 0x23) | ((kin & 0x10) >> 2) | ((kin & 0x0c) << 1);
  const size_t dbase = (size_t)((b * 8 + h) * 64 + dg) * L_SEQ + (l & ~63) + sl;
  for (int j = 0; j < 8; j++)
    vt[dbase + (size_t)j * L_SEQ] = ((const __hip_bfloat16*)&v)[j];
}

// ---------------- GEMM: C[M,N] = A[M,K] @ B[N,K]^T, bf16 in, fp32 accum ----------------
// Double-buffered LDS + counted vmcnt (T4): no vmcnt(0) drain in the K-loop.
// EPI 0: store bf16   1: += aux(fp32), store fp32   2: silu, store bf16   3: += aux(fp32), store fp32
template <int EPI>
__global__ __launch_bounds__(256) void gemm_kernel(const __hip_bfloat16* __restrict__ A,
                                                   const __hip_bfloat16* __restrict__ B,
                                                   int M, int N, int K,
                                                   const float* __restrict__ aux,
                                                   void* __restrict__ C) {
  __shared__ __align__(16) __hip_bfloat16 As[2][128 * 32];
  __shared__ __align__(16) __hip_bfloat16 Bs[2][128 * 32];
  const int tid = threadIdx.x;
  const int lane = tid & 63, w = tid >> 6;
  const int m0 = blockIdx.y * 128, n0 = blockIdx.x * 128;
  const int wm = (w >> 1) * 64, wn = (w & 1) * 64;
  const int r = lane & 15, q = lane >> 4;

  f32x4 acc[4][4];
  const f32x4 zz = {0.f, 0.f, 0.f, 0.f};
  for (int i = 0; i < 4; i++)
    for (int j = 0; j < 4; j++) acc[i][j] = zz;

  const int c0 = tid, c1 = 256 + tid;
  const int row0 = c0 >> 2, kb0 = (c0 & 3) * 8;
  const int row1 = c1 >> 2, kb1 = (c1 & 3) * 8;

#define GEMM_STAGE(k0, buf)                                                     \
  do {                                                                          \
    gl_lds16(A + (size_t)(m0 + row0) * K + ((k0) + kb0), &As[buf][c0 * 8]);     \
    gl_lds16(B + (size_t)(n0 + row0) * K + ((k0) + kb0), &Bs[buf][c0 * 8]);     \
    gl_lds16(A + (size_t)(m0 + row1) * K + ((k0) + kb1), &As[buf][c1 * 8]);     \
    gl_lds16(B + (size_t)(n0 + row1) * K + ((k0) + kb1), &Bs[buf][c1 * 8]);     \
  } while (0)

  GEMM_STAGE(0, 0);
  const int niter = K >> 5;
  for (int it = 0; it < niter; it++) {
    const int cur = it & 1;
    if (it + 1 < niter) {
      GEMM_STAGE((it + 1) << 5, cur ^ 1);
      asm volatile("s_waitcnt vmcnt(4)" ::: "memory");  // own iter-it loads retired
    } else {
      asm volatile("s_waitcnt vmcnt(0)" ::: "memory");
    }
    __builtin_amdgcn_s_barrier();  // all waves' iter-it stage complete
    bf16x8 af[4], bfr[4];
    for (int mi = 0; mi < 4; mi++)
      af[mi] = *(const bf16x8*)(&As[cur][(wm + mi * 16 + r) * 32 + q * 8]);
    for (int ni = 0; ni < 4; ni++)
      bfr[ni] = *(const bf16x8*)(&Bs[cur][(wn + ni * 16 + r) * 32 + q * 8]);
    for (int mi = 0; mi < 4; mi++)
      for (int ni = 0; ni < 4; ni++)
        acc[mi][ni] = __builtin_amdgcn_mfma_f32_16x16x32_bf16(af[mi], bfr[ni], acc[mi][ni], 0, 0, 0);
    __builtin_amdgcn_s_barrier();  // reads of buf[cur] done before it+1 overwrites it
  }
#undef GEMM_STAGE

  for (int mi = 0; mi < 4; mi++)
    for (int ni = 0; ni < 4; ni++)
      for (int j = 0; j < 4; j++) {
        const int gm = m0 + wm + mi * 16 + q * 4 + j;
        const int gn = n0 + wn + ni * 16 + r;
        float v = acc[mi][ni][j];
        const size_t idx = (size_t)gm * N + gn;
        if (EPI == 0) {
          ((__hip_bfloat16*)C)[idx] = f2bf(v);
        } else if (EPI == 1) {
          ((float*)C)[idx] = v + aux[idx];
        } else if (EPI == 2) {
          v = v / (1.0f + expf(-v));
          ((__hip_bfloat16*)C)[idx] = f2bf(v);
        } else {
          ((float*)C)[idx] = v + aux[idx];
        }
      }
}

// ---------------- Flash attention: swapped QK^T, lane-local P, fixed-ref softmax --------
// stage_kv: global_load_lds writes linearly; the 16B chunk index within each 128B row is
// XOR-swizzled on the GLOBAL source (chunk ^= row&7) and the same XOR is applied on the
// ds_read side -> conflict-free reads.
__device__ __forceinline__ void stage_kv(int w, int lane, int key0,
                                         const __hip_bfloat16* __restrict__ Kg,
                                         const __hip_bfloat16* __restrict__ Vg,
                                         __hip_bfloat16* Ks, __hip_bfloat16* Vs) {
  const int row_in = lane >> 3;        // 0..7
  const int cs = (lane & 7) ^ row_in;  // swizzled 16B-chunk index
#pragma unroll
  for (int ii = 0; ii < 2; ii++) {
    const int i = w * 2 + ii;          // instruction 0..7 across the 4 waves
    const int row = i * 8 + row_in;    // 0..63 (K: key index, V: dh index)
    gl_lds16(Kg + (size_t)(key0 + row) * QKV_LD + cs * 8, Ks + i * 512 + lane * 8);
    gl_lds16(Vg + (size_t)row * L_SEQ + key0 + cs * 8, Vs + i * 512 + lane * 8);
  }
}

// Swapped QK^T: s = mfma(A=K, B=Q) -> lane (r,q) holds S[key=16hc+4q+j][query=r].
// Fixed-reference log2-domain softmax: p = exp2(s*scale2 + biasH[key]); the per-row
// normalizer exp2(-bq) cancels in O/ls, the running max is unnecessary because
// |s*scale2| <~ 3 and biasH in [-1e30, +42] (t sorted, dfac*1000h/24*log2e ~ 42) keeps
// p within fp32/bf16 range. P stays in registers; sigma-permuted V makes each lane's
// p values exactly its PV A-fragment slots.
template <bool CAUSAL>
__device__ __forceinline__ void attn_tile(int key0, int lw0, int r, int q,
                                          const __hip_bfloat16* Ks,
                                          const __hip_bfloat16* Vs,
                                          const float* __restrict__ biasHp,
                                          float scale2,
                                          const bf16x8& qf0, const bf16x8& qf1,
                                          f32x4* o, float& ls) {
  const int r7 = r & 7;
  const f32x4 zz = {0.f, 0.f, 0.f, 0.f};
  f32x4 bias4[4];
#pragma unroll
  for (int hc = 0; hc < 4; hc++)
    bias4[hc] = *(const f32x4*)(biasHp + key0 + hc * 16 + q * 4);
  f32x4 s[4];
  __builtin_amdgcn_s_setprio(1);
#pragma unroll
  for (int hc = 0; hc < 4; hc++) {
    const __hip_bfloat16* kr = Ks + (hc * 16 + r) * 64;
    bf16x8 k0 = *(const bf16x8*)(kr + ((q ^ r7) * 8));
    bf16x8 k1 = *(const bf16x8*)(kr + (((q + 4) ^ r7) * 8));
    f32x4 a = zz;
    a = __builtin_amdgcn_mfma_f32_16x16x32_bf16(k0, qf0, a, 0, 0, 0);
    a = __builtin_amdgcn_mfma_f32_16x16x32_bf16(k1, qf1, a, 0, 0, 0);
    s[hc] = a;
  }
  __builtin_amdgcn_s_setprio(0);
  float p[4][4];
  float sum = 0.f;
#pragma unroll
  for (int hc = 0; hc < 4; hc++)
#pragma unroll
    for (int j = 0; j < 4; j++) {
      const float v = fmaf(s[hc][j], scale2, bias4[hc][j]);
      float pv = exp2f(v);
      if (CAUSAL) pv = (key0 + hc * 16 + q * 4 + j <= lw0 + r) ? pv : 0.f;
      p[hc][j] = pv;
      sum += pv;
    }
  ls += sum;
  // pack P (lane-local) into PV A-fragments; slot order matches sigma-permuted V columns
  bf16x8 pa[2];
#pragma unroll
  for (int kc = 0; kc < 2; kc++) {
    u32x4 pw;
    unsigned w0, w1, w2, w3;
    asm("v_cvt_pk_bf16_f32 %0, %1, %2" : "=v"(w0) : "v"(p[2 * kc][0]), "v"(p[2 * kc][1]));
    asm("v_cvt_pk_bf16_f32 %0, %1, %2" : "=v"(w1) : "v"(p[2 * kc][2]), "v"(p[2 * kc][3]));
    asm("v_cvt_pk_bf16_f32 %0, %1, %2" : "=v"(w2) : "v"(p[2 * kc + 1][0]), "v"(p[2 * kc + 1][1]));
    asm("v_cvt_pk_bf16_f32 %0, %1, %2" : "=v"(w3) : "v"(p[2 * kc + 1][2]), "v"(p[2 * kc + 1][3]));
    pw[0] = w0; pw[1] = w1; pw[2] = w2; pw[3] = w3;
    pa[kc] = *(bf16x8*)&pw;
  }
  __builtin_amdgcn_s_setprio(1);
#pragma unroll
  for (int kc = 0; kc < 2; kc++)
#pragma unroll
    for (int c = 0; c < 4; c++) {
      const __hip_bfloat16* vr = Vs + (c * 16 + r) * 64 + (((kc * 4 + q) ^ r7) * 8);
      bf16x8 vf = *(const bf16x8*)vr;
      o[c] = __builtin_amdgcn_mfma_f32_16x16x32_bf16(pa[kc], vf, o[c], 0, 0, 0);
    }
  __builtin_amdgcn_s_setprio(0);
}

// grid: 1024 blocks = exactly 4 resident/CU; balanced qi mapping so every CU's 4 blocks
// sum to 130 tiles. 4 waves/block share LDS-staged K/V; wave owns 16 q-rows.
__global__ __launch_bounds__(256, 4) void attn_kernel(const __hip_bfloat16* __restrict__ qkv,
                                                      const __hip_bfloat16* __restrict__ vt,
                                                      const float* __restrict__ biasH,
                                                      __hip_bfloat16* __restrict__ out) {
  const int blk = blockIdx.x;
  const int g = blk >> 4;  // 0..63
  const int bh = blk & 15;
  const int gm = g >> 4, gk = g & 15;
  const int qi = (gm == 0) ? gk : (gm == 1) ? 63 - gk : (gm == 2) ? 16 + gk : 47 - gk;
  const int b = bh >> 3, h = bh & 7;
  const int l0 = qi * 64;
  const int tid = threadIdx.x, lane = tid & 63, w = tid >> 6;
  const int lw0 = l0 + w * 16;
  const int r = lane & 15, q = lane >> 4;

  __shared__ __align__(16) __hip_bfloat16 Ksm[2][64 * 64];
  __shared__ __align__(16) __hip_bfloat16 Vsm[2][64 * 64];

  const float LOG2E = 1.4426950408889634f;
  const float scale2 = 0.125f * LOG2E;

  const __hip_bfloat16* Kg = qkv + (size_t)b * L_SEQ * QKV_LD + 512 + h * 64;
  const __hip_bfloat16* Vg = vt + (size_t)bh * 64 * L_SEQ;
  const float* biasHp = biasH + (size_t)bh * L_SEQ;

  // prologue: stage tile 0 while loading Q fragments
  stage_kv(w, lane, 0, Kg, Vg, Ksm[0], Vsm[0]);

  bf16x8 qf0, qf1;
  {
    const __hip_bfloat16* qrow = qkv + (size_t)(b * L_SEQ + lw0 + r) * QKV_LD + h * 64 + q * 8;
    qf0 = *(const bf16x8*)qrow;
    qf1 = *(const bf16x8*)(qrow + 32);
  }

  const f32x4 zz = {0.f, 0.f, 0.f, 0.f};
  f32x4 o[4];
  for (int c = 0; c < 4; c++) o[c] = zz;
  float ls = 0.f;

  const int ntiles = qi + 1;  // 64-key tiles, keys [0, l0+64); last tile is diagonal
  for (int t = 0; t < ntiles; t++) {
    const int cur = t & 1;
    if (t + 1 < ntiles) {
      stage_kv(w, lane, (t + 1) << 6, Kg, Vg, Ksm[cur ^ 1], Vsm[cur ^ 1]);
      asm volatile("s_waitcnt vmcnt(4)" ::: "memory");  // own tile-t stage retired
    } else {
      asm volatile("s_waitcnt vmcnt(0)" ::: "memory");
    }
    __builtin_amdgcn_s_barrier();  // all waves' tile-t stage complete
    if (t < ntiles - 1)
      attn_tile<false>(t << 6, lw0, r, q, Ksm[cur], Vsm[cur], biasHp, scale2, qf0, qf1, o, ls);
    else
      attn_tile<true>(t << 6, lw0, r, q, Ksm[cur], Vsm[cur], biasHp, scale2, qf0, qf1, o, ls);
    __builtin_amdgcn_s_barrier();  // reads of buf[cur] done before t+1 overwrites it
  }

  // ls lives per-lane for query r over this lane's key subset: reduce over q-lanes,
  // then redistribute to the O accumulator's query layout (q*4+j).
  float lt = ls;
  lt += __shfl_xor(lt, 16);
  lt += __shfl_xor(lt, 32);
  const float invr = 1.0f / lt;
  float invj[4];
  for (int j = 0; j < 4; j++) invj[j] = __shfl(invr, q * 4 + j);
  for (int c = 0; c < 4; c++)
    for (int j = 0; j < 4; j++) {
      const int rowg = lw0 + q * 4 + j;
      out[(size_t)(b * L_SEQ + rowg) * D_MODEL + h * 64 + c * 16 + r] = f2bf(o[c][j] * invj[j]);
    }
}

// ---------------- Launch ----------------
extern "C" void kernel_launch(void* const* d_in, const int* in_sizes, int n_in,
                              void* d_out, int out_size, void* d_ws, size_t ws_size,
                              hipStream_t stream) {
  const float* x = (const float*)d_in[0];
  const float* ts = (const float*)d_in[1];
  const float* mask = (const float*)d_in[2];
  const float* ln1_g = (const float*)d_in[3];
  const float* ln1_b = (const float*)d_in[4];
  const float* w_qkv = (const float*)d_in[5];
  const float* w_out = (const float*)d_in[6];
  const float* decay = (const float*)d_in[7];
  const float* ln2_g = (const float*)d_in[8];
  const float* ln2_b = (const float*)d_in[9];
  const float* w_ff1 = (const float*)d_in[10];
  const float* w_ff2 = (const float*)d_in[11];

  char* ws = (char*)d_ws;
  // layout (bytes) — total footprint 65,011,712 (identical to the last PASSING run):
  //   [0, 6M)    weights bf16
  //   [6M, 14M)  xn (dead after gemm0) -> vt overlays
  //   [14M, 38M) qkv (dead after attn)
  //   [38M, 46M) attnout -> h
  //   [46M, 62M) x2 (fp32) — biasH (256KB) lives at its HEAD: biasH is dead before
  //              gemm<1> writes x2 (disjoint lifetimes), so no extra ws is used.
  //   ff1out overlays [6M, 38M)
  __hip_bfloat16* wqkv_b = (__hip_bfloat16*)(ws + 0);
  __hip_bfloat16* wout_b = (__hip_bfloat16*)(ws + 1572864);
  __hip_bfloat16* wff1_b = (__hip_bfloat16*)(ws + 2097152);
  __hip_bfloat16* wff2_b = (__hip_bfloat16*)(ws + 4194304);
  __hip_bfloat16* xn = (__hip_bfloat16*)(ws + 6291456);
  __hip_bfloat16* vt = (__hip_bfloat16*)(ws + 6291456);
  __hip_bfloat16* qkv = (__hip_bfloat16*)(ws + 14680064);
  __hip_bfloat16* attnout = (__hip_bfloat16*)(ws + 39845888);
  __hip_bfloat16* h = attnout;
  __hip_bfloat16* ff1out = (__hip_bfloat16*)(ws + 6291456);
  float* x2 = (float*)(ws + 48234496);
  float* biasH = (float*)(ws + 48234496);  // overlays head of x2 (disjoint lifetime)
  float* out = (float*)d_out;

  const int M = 2 * L_SEQ;  // 8192

  cvt4_kernel<<<dim3(3072), dim3(256), 0, stream>>>(w_qkv, wqkv_b, w_out, wout_b,
                                                    w_ff1, wff1_b, w_ff2, wff2_b);
  bias_kernel<<<dim3(256), dim3(256), 0, stream>>>(ts, mask, decay, biasH);

  ln_kernel<<<dim3(M), dim3(256), 0, stream>>>(x, ln1_g, ln1_b, xn);
  gemm_kernel<0><<<dim3(12, 64), dim3(256), 0, stream>>>(xn, wqkv_b, M, 1536, 512, nullptr, qkv);
  vtrans_kernel<<<dim3(2048), dim3(256), 0, stream>>>(qkv, vt);
  attn_kernel<<<dim3(1024), dim3(256), 0, stream>>>(qkv, vt, biasH, attnout);
  gemm_kernel<1><<<dim3(4, 64), dim3(256), 0, stream>>>(attnout, wout_b, M, 512, 512, x, x2);
  ln_kernel<<<dim3(M), dim3(256), 0, stream>>>(x2, ln2_g, ln2_b, h);
  gemm_kernel<2><<<dim3(16, 64), dim3(256), 0, stream>>>(h, wff1_b, M, 2048, 512, nullptr, ff1out);
  gemm_kernel<3><<<dim3(4, 64), dim3(256), 0, stream>>>(ff1out, wff2_b, M, 512, 2048, x2, out);
}

// Round 5
// 302.604 us; speedup vs baseline: 1.7299x; 1.0154x over previous
//
#include <hip/hip_runtime.h>
#include <hip/hip_bf16.h>
#include <cmath>

// SparseAttentionBlock: B=2, L=4096, D=512, H=8, dh=64
// Inputs/outputs fp32; internal GEMM pipeline bf16; residual spine fp32.

#define L_SEQ 4096
#define D_MODEL 512
#define N_HEADS 8
#define D_HEAD 64
#define QKV_LD 1536

typedef __attribute__((ext_vector_type(8))) short bf16x8;
typedef __attribute__((ext_vector_type(4))) float f32x4;
typedef __attribute__((ext_vector_type(4))) unsigned u32x4;

__device__ __forceinline__ __hip_bfloat16 f2bf(float v) { return __float2bfloat16(v); }

__device__ __forceinline__ void gl_lds16(const __hip_bfloat16* g, __hip_bfloat16* l) {
  __builtin_amdgcn_global_load_lds((__attribute__((address_space(1))) void*)g,
                                   (__attribute__((address_space(3))) void*)l, 16, 0, 0);
}

// ---------------- fp32 -> bf16 convert: all 4 weight tensors in ONE launch ----------------
__global__ __launch_bounds__(256) void cvt4_kernel(const float* __restrict__ s0, __hip_bfloat16* __restrict__ d0,
                                                   const float* __restrict__ s1, __hip_bfloat16* __restrict__ d1,
                                                   const float* __restrict__ s2, __hip_bfloat16* __restrict__ d2,
                                                   const float* __restrict__ s3, __hip_bfloat16* __restrict__ d3) {
  const int i = blockIdx.x * 256 + threadIdx.x;  // grid 3072 -> 786432 float4s total
  const float* s;
  __hip_bfloat16* d;
  int off;
  if (i < 196608) { s = s0; d = d0; off = i; }
  else if (i < 262144) { s = s1; d = d1; off = i - 196608; }
  else if (i < 524288) { s = s2; d = d2; off = i - 262144; }
  else { s = s3; d = d3; off = i - 524288; }
  const float4 v = ((const float4*)s)[off];
  d[4 * off + 0] = f2bf(v.x);
  d[4 * off + 1] = f2bf(v.y);
  d[4 * off + 2] = f2bf(v.z);
  d[4 * off + 3] = f2bf(v.w);
}

// ---------------- per-(b,h) key bias: dfac_h * ts + mask fold (log2 domain) ----------------
__global__ __launch_bounds__(256) void bias_kernel(const float* __restrict__ ts,
                                                   const float* __restrict__ mask,
                                                   const float* __restrict__ decay_rate,
                                                   float* __restrict__ biasH) {
  const int idx = blockIdx.x * 256 + threadIdx.x;  // 65536 = 2*8*4096
  const int col = idx & 4095;
  const int h = (idx >> 12) & 7;
  const int b = idx >> 15;
  const float LOG2E = 1.4426950408889634f;
  const float dfac = log1pf(expf(decay_rate[h])) * (1.0f / 24.0f) * LOG2E;
  const float m = mask[b * 4096 + col];
  biasH[idx] = dfac * ts[b * 4096 + col] + (m != 0.f ? 0.f : -1e30f);
}

// ---------------- LayerNorm: fp32 in -> bf16 out ----------------
__global__ __launch_bounds__(256) void ln_kernel(const float* __restrict__ x,
                                                 const float* __restrict__ g,
                                                 const float* __restrict__ b,
                                                 __hip_bfloat16* __restrict__ out) {
  const int row = blockIdx.x;
  const int t = threadIdx.x;
  const float* xr = x + (size_t)row * D_MODEL;
  float v0 = xr[t];
  float v1 = xr[t + 256];
  float s = v0 + v1;
  float qq = v0 * v0 + v1 * v1;
  for (int off = 32; off > 0; off >>= 1) {
    s += __shfl_xor(s, off);
    qq += __shfl_xor(qq, off);
  }
  __shared__ float red[8];
  const int wid = t >> 6;
  if ((t & 63) == 0) { red[wid] = s; red[4 + wid] = qq; }
  __syncthreads();
  s = red[0] + red[1] + red[2] + red[3];
  qq = red[4] + red[5] + red[6] + red[7];
  const float mu = s * (1.0f / 512.0f);
  const float var = fmaxf(qq * (1.0f / 512.0f) - mu * mu, 0.0f);
  const float rstd = rsqrtf(var + 1e-5f);
  __hip_bfloat16* orow = out + (size_t)row * D_MODEL;
  orow[t] = f2bf((v0 - mu) * rstd * g[t] + b[t]);
  orow[t + 256] = f2bf((v1 - mu) * rstd * g[t + 256] + b[t + 256]);
}

// ---------------- V transpose: qkv V-region -> vt[b,h,dh, sigma-permuted L] ----------------
// sigma permutes key order WITHIN each 64-key tile (softmax is key-order invariant):
//   key bits [kc][a][q1][q0][j1][j0] -> slot [kc][q1][q0][a][j1][j0]
// so that after swapped QK^T each lane's own P values land in its own PV A-fragment slots.
__global__ __launch_bounds__(256) void vtrans_kernel(const __hip_bfloat16* __restrict__ qkv,
                                                     __hip_bfloat16* __restrict__ vt) {
  const int gid = blockIdx.x * 256 + threadIdx.x;  // 2*64*4096 threads exactly
  const int l = gid & 4095;
  const int bg = gid >> 12;
  const int b = bg >> 6, g = bg & 63;
  const int h = g >> 3, dg = (g & 7) * 8;
  const __hip_bfloat16* src = qkv + (size_t)(b * L_SEQ + l) * QKV_LD + 1024 + h * 64 + dg;
  bf16x8 v = *(const bf16x8*)src;
  const int kin = l & 63;
  const int sl = (kin & 0x23) | ((kin & 0x10) >> 2) | ((kin & 0x0c) << 1);
  const size_t dbase = (size_t)((b * 8 + h) * 64 + dg) * L_SEQ + (l & ~63) + sl;
  for (int j = 0; j < 8; j++)
    vt[dbase + (size_t)j * L_SEQ] = ((const __hip_bfloat16*)&v)[j];
}

// ---------------- GEMM 128x128: C[M,N] = A[M,K] @ B[N,K]^T, bf16 in, fp32 accum ---------
// Double-buffered LDS + counted vmcnt: no vmcnt(0) drain in the K-loop.
// EPI 0: store bf16   2: silu, store bf16
template <int EPI>
__global__ __launch_bounds__(256) void gemm_kernel(const __hip_bfloat16* __restrict__ A,
                                                   const __hip_bfloat16* __restrict__ B,
                                                   int M, int N, int K,
                                                   const float* __restrict__ aux,
                                                   void* __restrict__ C) {
  __shared__ __align__(16) __hip_bfloat16 As[2][128 * 32];
  __shared__ __align__(16) __hip_bfloat16 Bs[2][128 * 32];
  const int tid = threadIdx.x;
  const int lane = tid & 63, w = tid >> 6;
  const int m0 = blockIdx.y * 128, n0 = blockIdx.x * 128;
  const int wm = (w >> 1) * 64, wn = (w & 1) * 64;
  const int r = lane & 15, q = lane >> 4;

  f32x4 acc[4][4];
  const f32x4 zz = {0.f, 0.f, 0.f, 0.f};
  for (int i = 0; i < 4; i++)
    for (int j = 0; j < 4; j++) acc[i][j] = zz;

  const int c0 = tid, c1 = 256 + tid;
  const int row0 = c0 >> 2, kb0 = (c0 & 3) * 8;
  const int row1 = c1 >> 2, kb1 = (c1 & 3) * 8;

#define GEMM_STAGE(k0, buf)                                                     \
  do {                                                                          \
    gl_lds16(A + (size_t)(m0 + row0) * K + ((k0) + kb0), &As[buf][c0 * 8]);     \
    gl_lds16(B + (size_t)(n0 + row0) * K + ((k0) + kb0), &Bs[buf][c0 * 8]);     \
    gl_lds16(A + (size_t)(m0 + row1) * K + ((k0) + kb1), &As[buf][c1 * 8]);     \
    gl_lds16(B + (size_t)(n0 + row1) * K + ((k0) + kb1), &Bs[buf][c1 * 8]);     \
  } while (0)

  GEMM_STAGE(0, 0);
  const int niter = K >> 5;
  for (int it = 0; it < niter; it++) {
    const int cur = it & 1;
    if (it + 1 < niter) {
      GEMM_STAGE((it + 1) << 5, cur ^ 1);
      asm volatile("s_waitcnt vmcnt(4)" ::: "memory");  // own iter-it loads retired
    } else {
      asm volatile("s_waitcnt vmcnt(0)" ::: "memory");
    }
    __builtin_amdgcn_s_barrier();  // all waves' iter-it stage complete
    bf16x8 af[4], bfr[4];
    for (int mi = 0; mi < 4; mi++)
      af[mi] = *(const bf16x8*)(&As[cur][(wm + mi * 16 + r) * 32 + q * 8]);
    for (int ni = 0; ni < 4; ni++)
      bfr[ni] = *(const bf16x8*)(&Bs[cur][(wn + ni * 16 + r) * 32 + q * 8]);
    for (int mi = 0; mi < 4; mi++)
      for (int ni = 0; ni < 4; ni++)
        acc[mi][ni] = __builtin_amdgcn_mfma_f32_16x16x32_bf16(af[mi], bfr[ni], acc[mi][ni], 0, 0, 0);
    __builtin_amdgcn_s_barrier();  // reads of buf[cur] done before it+1 overwrites it
  }
#undef GEMM_STAGE

  for (int mi = 0; mi < 4; mi++)
    for (int ni = 0; ni < 4; ni++)
      for (int j = 0; j < 4; j++) {
        const int gm = m0 + wm + mi * 16 + q * 4 + j;
        const int gn = n0 + wn + ni * 16 + r;
        float v = acc[mi][ni][j];
        const size_t idx = (size_t)gm * N + gn;
        if (EPI == 0) {
          ((__hip_bfloat16*)C)[idx] = f2bf(v);
        } else {
          v = v / (1.0f + expf(-v));
          ((__hip_bfloat16*)C)[idx] = f2bf(v);
        }
      }
}

// ---------------- GEMM 64x128 (+residual fp32 epilogue) for N=512 shapes -----------------
// gemm1/gemm3 at 128x128 gave grid=256 blocks = 1 block/CU = 1 wave/SIMD -> latency-bound.
// BM=64 doubles the grid to 512 blocks (2/CU). 3 stage-loads/thread -> vmcnt(3).
__global__ __launch_bounds__(256) void gemm_res64_kernel(const __hip_bfloat16* __restrict__ A,
                                                         const __hip_bfloat16* __restrict__ B,
                                                         int M, int N, int K,
                                                         const float* __restrict__ aux,
                                                         float* __restrict__ C) {
  __shared__ __align__(16) __hip_bfloat16 As[2][64 * 32];
  __shared__ __align__(16) __hip_bfloat16 Bs[2][128 * 32];
  const int tid = threadIdx.x;
  const int lane = tid & 63, w = tid >> 6;
  const int m0 = blockIdx.y * 64, n0 = blockIdx.x * 128;
  const int wm = (w >> 1) * 32, wn = (w & 1) * 64;
  const int r = lane & 15, q = lane >> 4;

  f32x4 acc[2][4];
  const f32x4 zz = {0.f, 0.f, 0.f, 0.f};
  for (int i = 0; i < 2; i++)
    for (int j = 0; j < 4; j++) acc[i][j] = zz;

  const int rowA = tid >> 2, kbA = (tid & 3) * 8;     // A: 64 rows x 4 chunks = 256
  const int c0 = tid, c1 = 256 + tid;                 // B: 128 rows x 4 chunks = 512
  const int rowB0 = c0 >> 2, kb0 = (c0 & 3) * 8;
  const int rowB1 = c1 >> 2, kb1 = (c1 & 3) * 8;

#define GEMM_STAGE64(k0, buf)                                                    \
  do {                                                                           \
    gl_lds16(A + (size_t)(m0 + rowA) * K + ((k0) + kbA), &As[buf][tid * 8]);     \
    gl_lds16(B + (size_t)(n0 + rowB0) * K + ((k0) + kb0), &Bs[buf][c0 * 8]);     \
    gl_lds16(B + (size_t)(n0 + rowB1) * K + ((k0) + kb1), &Bs[buf][c1 * 8]);     \
  } while (0)

  GEMM_STAGE64(0, 0);
  const int niter = K >> 5;
  for (int it = 0; it < niter; it++) {
    const int cur = it & 1;
    if (it + 1 < niter) {
      GEMM_STAGE64((it + 1) << 5, cur ^ 1);
      asm volatile("s_waitcnt vmcnt(3)" ::: "memory");  // own iter-it loads retired
    } else {
      asm volatile("s_waitcnt vmcnt(0)" ::: "memory");
    }
    __builtin_amdgcn_s_barrier();
    bf16x8 af[2], bfr[4];
    for (int mi = 0; mi < 2; mi++)
      af[mi] = *(const bf16x8*)(&As[cur][(wm + mi * 16 + r) * 32 + q * 8]);
    for (int ni = 0; ni < 4; ni++)
      bfr[ni] = *(const bf16x8*)(&Bs[cur][(wn + ni * 16 + r) * 32 + q * 8]);
    for (int mi = 0; mi < 2; mi++)
      for (int ni = 0; ni < 4; ni++)
        acc[mi][ni] = __builtin_amdgcn_mfma_f32_16x16x32_bf16(af[mi], bfr[ni], acc[mi][ni], 0, 0, 0);
    __builtin_amdgcn_s_barrier();
  }
#undef GEMM_STAGE64

  for (int mi = 0; mi < 2; mi++)
    for (int ni = 0; ni < 4; ni++)
      for (int j = 0; j < 4; j++) {
        const int gm = m0 + wm + mi * 16 + q * 4 + j;
        const int gn = n0 + wn + ni * 16 + r;
        const size_t idx = (size_t)gm * N + gn;
        C[idx] = acc[mi][ni][j] + aux[idx];
      }
}

// ---------------- Flash attention: swapped QK^T, lane-local P, fixed-ref softmax --------
// stage_kv: global_load_lds writes linearly; the 16B chunk index within each 128B row is
// XOR-swizzled on the GLOBAL source (chunk ^= row&7) and the same XOR is applied on the
// ds_read side -> conflict-free reads.
__device__ __forceinline__ void stage_kv(int w, int lane, int key0,
                                         const __hip_bfloat16* __restrict__ Kg,
                                         const __hip_bfloat16* __restrict__ Vg,
                                         __hip_bfloat16* Ks, __hip_bfloat16* Vs) {
  const int row_in = lane >> 3;        // 0..7
  const int cs = (lane & 7) ^ row_in;  // swizzled 16B-chunk index
#pragma unroll
  for (int ii = 0; ii < 2; ii++) {
    const int i = w * 2 + ii;          // instruction 0..7 across the 4 waves
    const int row = i * 8 + row_in;    // 0..63 (K: key index, V: dh index)
    gl_lds16(Kg + (size_t)(key0 + row) * QKV_LD + cs * 8, Ks + i * 512 + lane * 8);
    gl_lds16(Vg + (size_t)row * L_SEQ + key0 + cs * 8, Vs + i * 512 + lane * 8);
  }
}

// Swapped QK^T: s = mfma(A=K, B=Q) -> lane (r,q) holds S[key=16hc+4q+j][query=r].
// Fixed-reference log2-domain softmax: p = exp2(s*scale2 + biasH[key]); per-row
// normalizer cancels in O/ls; biasH bounded (+42 max) keeps p in fp32/bf16 range.
// P stays in registers; sigma-permuted V makes each lane's p values its PV A-fragment.
template <bool CAUSAL>
__device__ __forceinline__ void attn_tile(int key0, int lw0, int r, int q,
                                          const __hip_bfloat16* Ks,
                                          const __hip_bfloat16* Vs,
                                          const float* __restrict__ biasHp,
                                          float scale2,
                                          const bf16x8& qf0, const bf16x8& qf1,
                                          f32x4* o, float& ls) {
  const int r7 = r & 7;
  const f32x4 zz = {0.f, 0.f, 0.f, 0.f};
  f32x4 bias4[4];
#pragma unroll
  for (int hc = 0; hc < 4; hc++)
    bias4[hc] = *(const f32x4*)(biasHp + key0 + hc * 16 + q * 4);
  f32x4 s[4];
  __builtin_amdgcn_s_setprio(1);
#pragma unroll
  for (int hc = 0; hc < 4; hc++) {
    const __hip_bfloat16* kr = Ks + (hc * 16 + r) * 64;
    bf16x8 k0 = *(const bf16x8*)(kr + ((q ^ r7) * 8));
    bf16x8 k1 = *(const bf16x8*)(kr + (((q + 4) ^ r7) * 8));
    f32x4 a = zz;
    a = __builtin_amdgcn_mfma_f32_16x16x32_bf16(k0, qf0, a, 0, 0, 0);
    a = __builtin_amdgcn_mfma_f32_16x16x32_bf16(k1, qf1, a, 0, 0, 0);
    s[hc] = a;
  }
  __builtin_amdgcn_s_setprio(0);
  float p[4][4];
  float sum = 0.f;
#pragma unroll
  for (int hc = 0; hc < 4; hc++)
#pragma unroll
    for (int j = 0; j < 4; j++) {
      const float v = fmaf(s[hc][j], scale2, bias4[hc][j]);
      float pv = exp2f(v);
      if (CAUSAL) pv = (key0 + hc * 16 + q * 4 + j <= lw0 + r) ? pv : 0.f;
      p[hc][j] = pv;
      sum += pv;
    }
  ls += sum;
  // pack P (lane-local) into PV A-fragments; slot order matches sigma-permuted V columns
  bf16x8 pa[2];
#pragma unroll
  for (int kc = 0; kc < 2; kc++) {
    u32x4 pw;
    unsigned w0, w1, w2, w3;
    asm("v_cvt_pk_bf16_f32 %0, %1, %2" : "=v"(w0) : "v"(p[2 * kc][0]), "v"(p[2 * kc][1]));
    asm("v_cvt_pk_bf16_f32 %0, %1, %2" : "=v"(w1) : "v"(p[2 * kc][2]), "v"(p[2 * kc][3]));
    asm("v_cvt_pk_bf16_f32 %0, %1, %2" : "=v"(w2) : "v"(p[2 * kc + 1][0]), "v"(p[2 * kc + 1][1]));
    asm("v_cvt_pk_bf16_f32 %0, %1, %2" : "=v"(w3) : "v"(p[2 * kc + 1][2]), "v"(p[2 * kc + 1][3]));
    pw[0] = w0; pw[1] = w1; pw[2] = w2; pw[3] = w3;
    pa[kc] = *(bf16x8*)&pw;
  }
  __builtin_amdgcn_s_setprio(1);
#pragma unroll
  for (int kc = 0; kc < 2; kc++)
#pragma unroll
    for (int c = 0; c < 4; c++) {
      const __hip_bfloat16* vr = Vs + (c * 16 + r) * 64 + (((kc * 4 + q) ^ r7) * 8);
      bf16x8 vf = *(const bf16x8*)vr;
      o[c] = __builtin_amdgcn_mfma_f32_16x16x32_bf16(pa[kc], vf, o[c], 0, 0, 0);
    }
  __builtin_amdgcn_s_setprio(0);
}

// grid: 512 UNIFORM blocks: block (bh, pr) does q-tile pr (pr+1 key-tiles) THEN q-tile
// 63-pr (64-pr key-tiles) = exactly 65 tiles/block -> per-CU load is identical under ANY
// block->CU assignment (round-robin, chunked, whatever). Double-buffering continues
// across the phase boundary (phase-B tile 0 staged as the "next" of phase A's last tile).
__global__ __launch_bounds__(256, 2) void attn_kernel(const __hip_bfloat16* __restrict__ qkv,
                                                      const __hip_bfloat16* __restrict__ vt,
                                                      const float* __restrict__ biasH,
                                                      __hip_bfloat16* __restrict__ out) {
  const int blk = blockIdx.x;
  const int bh = blk & 15;
  const int pr = blk >> 4;  // 0..31
  const int b = bh >> 3, h = bh & 7;
  const int qiA = pr, qiB = 63 - pr;
  const int l0A = qiA * 64, l0B = qiB * 64;
  const int tid = threadIdx.x, lane = tid & 63, w = tid >> 6;
  const int lw0A = l0A + w * 16, lw0B = l0B + w * 16;
  const int r = lane & 15, q = lane >> 4;

  __shared__ __align__(16) __hip_bfloat16 Ksm[2][64 * 64];
  __shared__ __align__(16) __hip_bfloat16 Vsm[2][64 * 64];

  const float LOG2E = 1.4426950408889634f;
  const float scale2 = 0.125f * LOG2E;

  const __hip_bfloat16* Kg = qkv + (size_t)b * L_SEQ * QKV_LD + 512 + h * 64;
  const __hip_bfloat16* Vg = vt + (size_t)bh * 64 * L_SEQ;
  const float* biasHp = biasH + (size_t)bh * L_SEQ;

  // prologue: stage phase-A tile 0 while loading Q fragments for both phases
  stage_kv(w, lane, 0, Kg, Vg, Ksm[0], Vsm[0]);

  bf16x8 qfA0, qfA1, qfB0, qfB1;
  {
    const __hip_bfloat16* qrA = qkv + (size_t)(b * L_SEQ + lw0A + r) * QKV_LD + h * 64 + q * 8;
    qfA0 = *(const bf16x8*)qrA;
    qfA1 = *(const bf16x8*)(qrA + 32);
    const __hip_bfloat16* qrB = qkv + (size_t)(b * L_SEQ + lw0B + r) * QKV_LD + h * 64 + q * 8;
    qfB0 = *(const bf16x8*)qrB;
    qfB1 = *(const bf16x8*)(qrB + 32);
  }

  const f32x4 zz = {0.f, 0.f, 0.f, 0.f};
  f32x4 o[4];
  for (int c = 0; c < 4; c++) o[c] = zz;
  float ls = 0.f;

  const int ntA = qiA + 1;  // phase-A key-tiles (last is diagonal)
  const int ntB = qiB + 1;  // phase-B key-tiles (last is diagonal)

  // ---- phase A ---- (always stages a "next": phase-B tile 0 follows A's last tile)
  for (int t = 0; t < ntA; t++) {
    const int cur = t & 1;
    const int nxt_key0 = (t + 1 < ntA) ? ((t + 1) << 6) : 0;  // B's tile 0 after A's last
    stage_kv(w, lane, nxt_key0, Kg, Vg, Ksm[cur ^ 1], Vsm[cur ^ 1]);
    asm volatile("s_waitcnt vmcnt(4)" ::: "memory");  // own tile-t stage retired
    __builtin_amdgcn_s_barrier();                     // all waves' tile-t stage complete
    if (t < ntA - 1)
      attn_tile<false>(t << 6, lw0A, r, q, Ksm[cur], Vsm[cur], biasHp, scale2, qfA0, qfA1, o, ls);
    else
      attn_tile<true>(t << 6, lw0A, r, q, Ksm[cur], Vsm[cur], biasHp, scale2, qfA0, qfA1, o, ls);
    __builtin_amdgcn_s_barrier();  // reads of buf[cur] done before next stage overwrites
  }

  // ---- phase A epilogue: normalize + store, reset accumulators ----
  {
    float lt = ls;
    lt += __shfl_xor(lt, 16);
    lt += __shfl_xor(lt, 32);
    const float invr = 1.0f / lt;
    float invj[4];
    for (int j = 0; j < 4; j++) invj[j] = __shfl(invr, q * 4 + j);
    for (int c = 0; c < 4; c++)
      for (int j = 0; j < 4; j++) {
        const int rowg = lw0A + q * 4 + j;
        out[(size_t)(b * L_SEQ + rowg) * D_MODEL + h * 64 + c * 16 + r] = f2bf(o[c][j] * invj[j]);
      }
    for (int c = 0; c < 4; c++) o[c] = zz;
    ls = 0.f;
  }

  // ---- phase B ---- (buffer parity continues: tile t uses buf (ntA + t) & 1)
  for (int t = 0; t < ntB; t++) {
    const int cur = (ntA + t) & 1;
    if (t + 1 < ntB) {
      stage_kv(w, lane, (t + 1) << 6, Kg, Vg, Ksm[cur ^ 1], Vsm[cur ^ 1]);
      asm volatile("s_waitcnt vmcnt(4)" ::: "memory");
    } else {
      asm volatile("s_waitcnt vmcnt(0)" ::: "memory");
    }
    __builtin_amdgcn_s_barrier();
    if (t < ntB - 1)
      attn_tile<false>(t << 6, lw0B, r, q, Ksm[cur], Vsm[cur], biasHp, scale2, qfB0, qfB1, o, ls);
    else
      attn_tile<true>(t << 6, lw0B, r, q, Ksm[cur], Vsm[cur], biasHp, scale2, qfB0, qfB1, o, ls);
    __builtin_amdgcn_s_barrier();
  }

  // ---- phase B epilogue ----
  {
    float lt = ls;
    lt += __shfl_xor(lt, 16);
    lt += __shfl_xor(lt, 32);
    const float invr = 1.0f / lt;
    float invj[4];
    for (int j = 0; j < 4; j++) invj[j] = __shfl(invr, q * 4 + j);
    for (int c = 0; c < 4; c++)
      for (int j = 0; j < 4; j++) {
        const int rowg = lw0B + q * 4 + j;
        out[(size_t)(b * L_SEQ + rowg) * D_MODEL + h * 64 + c * 16 + r] = f2bf(o[c][j] * invj[j]);
      }
  }
}

// ---------------- Launch ----------------
extern "C" void kernel_launch(void* const* d_in, const int* in_sizes, int n_in,
                              void* d_out, int out_size, void* d_ws, size_t ws_size,
                              hipStream_t stream) {
  const float* x = (const float*)d_in[0];
  const float* ts = (const float*)d_in[1];
  const float* mask = (const float*)d_in[2];
  const float* ln1_g = (const float*)d_in[3];
  const float* ln1_b = (const float*)d_in[4];
  const float* w_qkv = (const float*)d_in[5];
  const float* w_out = (const float*)d_in[6];
  const float* decay = (const float*)d_in[7];
  const float* ln2_g = (const float*)d_in[8];
  const float* ln2_b = (const float*)d_in[9];
  const float* w_ff1 = (const float*)d_in[10];
  const float* w_ff2 = (const float*)d_in[11];

  char* ws = (char*)d_ws;
  // layout (bytes) — total footprint 65,011,712:
  //   [0, 6M)    weights bf16
  //   [6M, 14M)  xn (dead after gemm0) -> vt overlays
  //   [14M, 38M) qkv (dead after attn)
  //   [38M, 46M) attnout -> h
  //   [46M, 62M) x2 (fp32) — biasH (256KB) lives at its HEAD: biasH is dead before
  //              gemm<1> writes x2 (disjoint lifetimes), so no extra ws is used.
  //   ff1out overlays [6M, 38M)
  __hip_bfloat16* wqkv_b = (__hip_bfloat16*)(ws + 0);
  __hip_bfloat16* wout_b = (__hip_bfloat16*)(ws + 1572864);
  __hip_bfloat16* wff1_b = (__hip_bfloat16*)(ws + 2097152);
  __hip_bfloat16* wff2_b = (__hip_bfloat16*)(ws + 4194304);
  __hip_bfloat16* xn = (__hip_bfloat16*)(ws + 6291456);
  __hip_bfloat16* vt = (__hip_bfloat16*)(ws + 6291456);
  __hip_bfloat16* qkv = (__hip_bfloat16*)(ws + 14680064);
  __hip_bfloat16* attnout = (__hip_bfloat16*)(ws + 39845888);
  __hip_bfloat16* h = attnout;
  __hip_bfloat16* ff1out = (__hip_bfloat16*)(ws + 6291456);
  float* x2 = (float*)(ws + 48234496);
  float* biasH = (float*)(ws + 48234496);  // overlays head of x2 (disjoint lifetime)
  float* out = (float*)d_out;

  const int M = 2 * L_SEQ;  // 8192

  cvt4_kernel<<<dim3(3072), dim3(256), 0, stream>>>(w_qkv, wqkv_b, w_out, wout_b,
                                                    w_ff1, wff1_b, w_ff2, wff2_b);
  bias_kernel<<<dim3(256), dim3(256), 0, stream>>>(ts, mask, decay, biasH);

  ln_kernel<<<dim3(M), dim3(256), 0, stream>>>(x, ln1_g, ln1_b, xn);
  gemm_kernel<0><<<dim3(12, 64), dim3(256), 0, stream>>>(xn, wqkv_b, M, 1536, 512, nullptr, qkv);
  vtrans_kernel<<<dim3(2048), dim3(256), 0, stream>>>(qkv, vt);
  attn_kernel<<<dim3(512), dim3(256), 0, stream>>>(qkv, vt, biasH, attnout);
  gemm_res64_kernel<<<dim3(4, 128), dim3(256), 0, stream>>>(attnout, wout_b, M, 512, 512, x, x2);
  ln_kernel<<<dim3(M), dim3(256), 0, stream>>>(x2, ln2_g, ln2_b, h);
  gemm_kernel<2><<<dim3(16, 64), dim3(256), 0, stream>>>(h, wff1_b, M, 2048, 512, nullptr, ff1out);
  gemm_res64_kernel<<<dim3(4, 128), dim3(256), 0, stream>>>(ff1out, wff2_b, M, 512, 2048, x2, out);
}

// Round 6
// 293.907 us; speedup vs baseline: 1.7811x; 1.0296x over previous
//
#include <hip/hip_runtime.h>
#include <hip/hip_bf16.h>
#include <cmath>

// SparseAttentionBlock: B=2, L=4096, D=512, H=8, dh=64
// Inputs/outputs fp32; internal GEMM pipeline bf16; residual spine fp32.

#define L_SEQ 4096
#define D_MODEL 512
#define N_HEADS 8
#define D_HEAD 64
#define QKV_LD 1536

typedef __attribute__((ext_vector_type(8))) short bf16x8;
typedef __attribute__((ext_vector_type(4))) float f32x4;
typedef __attribute__((ext_vector_type(4))) unsigned u32x4;

__device__ __forceinline__ __hip_bfloat16 f2bf(float v) { return __float2bfloat16(v); }

__device__ __forceinline__ void gl_lds16(const __hip_bfloat16* g, __hip_bfloat16* l) {
  __builtin_amdgcn_global_load_lds((__attribute__((address_space(1))) void*)g,
                                   (__attribute__((address_space(3))) void*)l, 16, 0, 0);
}

// ---------------- fp32 -> bf16 convert (4 weight tensors) + bias prep, ONE launch --------
__global__ __launch_bounds__(256) void cvt4b_kernel(const float* __restrict__ s0, __hip_bfloat16* __restrict__ d0,
                                                    const float* __restrict__ s1, __hip_bfloat16* __restrict__ d1,
                                                    const float* __restrict__ s2, __hip_bfloat16* __restrict__ d2,
                                                    const float* __restrict__ s3, __hip_bfloat16* __restrict__ d3,
                                                    const float* __restrict__ ts,
                                                    const float* __restrict__ mask,
                                                    const float* __restrict__ decay_rate,
                                                    float* __restrict__ biasH) {
  const int i = blockIdx.x * 256 + threadIdx.x;  // grid 3328
  if (i < 786432) {
    const float* s;
    __hip_bfloat16* d;
    int off;
    if (i < 196608) { s = s0; d = d0; off = i; }
    else if (i < 262144) { s = s1; d = d1; off = i - 196608; }
    else if (i < 524288) { s = s2; d = d2; off = i - 262144; }
    else { s = s3; d = d3; off = i - 524288; }
    const float4 v = ((const float4*)s)[off];
    d[4 * off + 0] = f2bf(v.x);
    d[4 * off + 1] = f2bf(v.y);
    d[4 * off + 2] = f2bf(v.z);
    d[4 * off + 3] = f2bf(v.w);
  } else {
    const int idx = i - 786432;  // 65536 = 2*8*4096
    const int col = idx & 4095;
    const int h = (idx >> 12) & 7;
    const int b = idx >> 15;
    const float LOG2E = 1.4426950408889634f;
    const float dfac = log1pf(expf(decay_rate[h])) * (1.0f / 24.0f) * LOG2E;
    const float m = mask[b * 4096 + col];
    biasH[idx] = dfac * ts[b * 4096 + col] + (m != 0.f ? 0.f : -1e30f);
  }
}

// ---------------- LayerNorm: fp32 in -> bf16 out ----------------
__global__ __launch_bounds__(256) void ln_kernel(const float* __restrict__ x,
                                                 const float* __restrict__ g,
                                                 const float* __restrict__ b,
                                                 __hip_bfloat16* __restrict__ out) {
  const int row = blockIdx.x;
  const int t = threadIdx.x;
  const float* xr = x + (size_t)row * D_MODEL;
  float v0 = xr[t];
  float v1 = xr[t + 256];
  float s = v0 + v1;
  float qq = v0 * v0 + v1 * v1;
  for (int off = 32; off > 0; off >>= 1) {
    s += __shfl_xor(s, off);
    qq += __shfl_xor(qq, off);
  }
  __shared__ float red[8];
  const int wid = t >> 6;
  if ((t & 63) == 0) { red[wid] = s; red[4 + wid] = qq; }
  __syncthreads();
  s = red[0] + red[1] + red[2] + red[3];
  qq = red[4] + red[5] + red[6] + red[7];
  const float mu = s * (1.0f / 512.0f);
  const float var = fmaxf(qq * (1.0f / 512.0f) - mu * mu, 0.0f);
  const float rstd = rsqrtf(var + 1e-5f);
  __hip_bfloat16* orow = out + (size_t)row * D_MODEL;
  orow[t] = f2bf((v0 - mu) * rstd * g[t] + b[t]);
  orow[t + 256] = f2bf((v1 - mu) * rstd * g[t + 256] + b[t + 256]);
}

// ---------------- V transpose: qkv V-region -> vt[b,h,dh, sigma-permuted L] ----------------
// sigma permutes key order WITHIN each 64-key tile (softmax is key-order invariant):
//   key bits [kc][a][q1][q0][j1][j0] -> slot [kc][q1][q0][a][j1][j0]
// so that after swapped QK^T each lane's own P values land in its own PV A-fragment slots.
__global__ __launch_bounds__(256) void vtrans_kernel(const __hip_bfloat16* __restrict__ qkv,
                                                     __hip_bfloat16* __restrict__ vt) {
  const int gid = blockIdx.x * 256 + threadIdx.x;  // 2*64*4096 threads exactly
  const int l = gid & 4095;
  const int bg = gid >> 12;
  const int b = bg >> 6, g = bg & 63;
  const int h = g >> 3, dg = (g & 7) * 8;
  const __hip_bfloat16* src = qkv + (size_t)(b * L_SEQ + l) * QKV_LD + 1024 + h * 64 + dg;
  bf16x8 v = *(const bf16x8*)src;
  const int kin = l & 63;
  const int sl = (kin & 0x23) | ((kin & 0x10) >> 2) | ((kin & 0x0c) << 1);
  const size_t dbase = (size_t)((b * 8 + h) * 64 + dg) * L_SEQ + (l & ~63) + sl;
  for (int j = 0; j < 8; j++)
    vt[dbase + (size_t)j * L_SEQ] = ((const __hip_bfloat16*)&v)[j];
}

// ---------------- GEMM 128x128: C[M,N] = A[M,K] @ B[N,K]^T, bf16 in, fp32 accum ---------
// Double-buffered LDS + counted vmcnt: no vmcnt(0) drain in the K-loop.
// EPI 0: store bf16   2: silu, store bf16
template <int EPI>
__global__ __launch_bounds__(256) void gemm_kernel(const __hip_bfloat16* __restrict__ A,
                                                   const __hip_bfloat16* __restrict__ B,
                                                   int M, int N, int K,
                                                   const float* __restrict__ aux,
                                                   void* __restrict__ C) {
  __shared__ __align__(16) __hip_bfloat16 As[2][128 * 32];
  __shared__ __align__(16) __hip_bfloat16 Bs[2][128 * 32];
  const int tid = threadIdx.x;
  const int lane = tid & 63, w = tid >> 6;
  const int m0 = blockIdx.y * 128, n0 = blockIdx.x * 128;
  const int wm = (w >> 1) * 64, wn = (w & 1) * 64;
  const int r = lane & 15, q = lane >> 4;

  f32x4 acc[4][4];
  const f32x4 zz = {0.f, 0.f, 0.f, 0.f};
  for (int i = 0; i < 4; i++)
    for (int j = 0; j < 4; j++) acc[i][j] = zz;

  const int c0 = tid, c1 = 256 + tid;
  const int row0 = c0 >> 2, kb0 = (c0 & 3) * 8;
  const int row1 = c1 >> 2, kb1 = (c1 & 3) * 8;

#define GEMM_STAGE(k0, buf)                                                     \
  do {                                                                          \
    gl_lds16(A + (size_t)(m0 + row0) * K + ((k0) + kb0), &As[buf][c0 * 8]);     \
    gl_lds16(B + (size_t)(n0 + row0) * K + ((k0) + kb0), &Bs[buf][c0 * 8]);     \
    gl_lds16(A + (size_t)(m0 + row1) * K + ((k0) + kb1), &As[buf][c1 * 8]);     \
    gl_lds16(B + (size_t)(n0 + row1) * K + ((k0) + kb1), &Bs[buf][c1 * 8]);     \
  } while (0)

  GEMM_STAGE(0, 0);
  const int niter = K >> 5;
  for (int it = 0; it < niter; it++) {
    const int cur = it & 1;
    if (it + 1 < niter) {
      GEMM_STAGE((it + 1) << 5, cur ^ 1);
      asm volatile("s_waitcnt vmcnt(4)" ::: "memory");  // own iter-it loads retired
    } else {
      asm volatile("s_waitcnt vmcnt(0)" ::: "memory");
    }
    __builtin_amdgcn_s_barrier();  // all waves' iter-it stage complete
    bf16x8 af[4], bfr[4];
    for (int mi = 0; mi < 4; mi++)
      af[mi] = *(const bf16x8*)(&As[cur][(wm + mi * 16 + r) * 32 + q * 8]);
    for (int ni = 0; ni < 4; ni++)
      bfr[ni] = *(const bf16x8*)(&Bs[cur][(wn + ni * 16 + r) * 32 + q * 8]);
    for (int mi = 0; mi < 4; mi++)
      for (int ni = 0; ni < 4; ni++)
        acc[mi][ni] = __builtin_amdgcn_mfma_f32_16x16x32_bf16(af[mi], bfr[ni], acc[mi][ni], 0, 0, 0);
    __builtin_amdgcn_s_barrier();  // reads of buf[cur] done before it+1 overwrites it
  }
#undef GEMM_STAGE

  for (int mi = 0; mi < 4; mi++)
    for (int ni = 0; ni < 4; ni++)
      for (int j = 0; j < 4; j++) {
        const int gm = m0 + wm + mi * 16 + q * 4 + j;
        const int gn = n0 + wn + ni * 16 + r;
        float v = acc[mi][ni][j];
        const size_t idx = (size_t)gm * N + gn;
        if (EPI == 0) {
          ((__hip_bfloat16*)C)[idx] = f2bf(v);
        } else {
          v = v / (1.0f + expf(-v));
          ((__hip_bfloat16*)C)[idx] = f2bf(v);
        }
      }
}

// ---------------- GEMM 64x128 (+residual fp32 epilogue) for N=512 shapes -----------------
__global__ __launch_bounds__(256) void gemm_res64_kernel(const __hip_bfloat16* __restrict__ A,
                                                         const __hip_bfloat16* __restrict__ B,
                                                         int M, int N, int K,
                                                         const float* __restrict__ aux,
                                                         float* __restrict__ C) {
  __shared__ __align__(16) __hip_bfloat16 As[2][64 * 32];
  __shared__ __align__(16) __hip_bfloat16 Bs[2][128 * 32];
  const int tid = threadIdx.x;
  const int lane = tid & 63, w = tid >> 6;
  const int m0 = blockIdx.y * 64, n0 = blockIdx.x * 128;
  const int wm = (w >> 1) * 32, wn = (w & 1) * 64;
  const int r = lane & 15, q = lane >> 4;

  f32x4 acc[2][4];
  const f32x4 zz = {0.f, 0.f, 0.f, 0.f};
  for (int i = 0; i < 2; i++)
    for (int j = 0; j < 4; j++) acc[i][j] = zz;

  const int rowA = tid >> 2, kbA = (tid & 3) * 8;     // A: 64 rows x 4 chunks = 256
  const int c0 = tid, c1 = 256 + tid;                 // B: 128 rows x 4 chunks = 512
  const int rowB0 = c0 >> 2, kb0 = (c0 & 3) * 8;
  const int rowB1 = c1 >> 2, kb1 = (c1 & 3) * 8;

#define GEMM_STAGE64(k0, buf)                                                    \
  do {                                                                           \
    gl_lds16(A + (size_t)(m0 + rowA) * K + ((k0) + kbA), &As[buf][tid * 8]);     \
    gl_lds16(B + (size_t)(n0 + rowB0) * K + ((k0) + kb0), &Bs[buf][c0 * 8]);     \
    gl_lds16(B + (size_t)(n0 + rowB1) * K + ((k0) + kb1), &Bs[buf][c1 * 8]);     \
  } while (0)

  GEMM_STAGE64(0, 0);
  const int niter = K >> 5;
  for (int it = 0; it < niter; it++) {
    const int cur = it & 1;
    if (it + 1 < niter) {
      GEMM_STAGE64((it + 1) << 5, cur ^ 1);
      asm volatile("s_waitcnt vmcnt(3)" ::: "memory");  // own iter-it loads retired
    } else {
      asm volatile("s_waitcnt vmcnt(0)" ::: "memory");
    }
    __builtin_amdgcn_s_barrier();
    bf16x8 af[2], bfr[4];
    for (int mi = 0; mi < 2; mi++)
      af[mi] = *(const bf16x8*)(&As[cur][(wm + mi * 16 + r) * 32 + q * 8]);
    for (int ni = 0; ni < 4; ni++)
      bfr[ni] = *(const bf16x8*)(&Bs[cur][(wn + ni * 16 + r) * 32 + q * 8]);
    for (int mi = 0; mi < 2; mi++)
      for (int ni = 0; ni < 4; ni++)
        acc[mi][ni] = __builtin_amdgcn_mfma_f32_16x16x32_bf16(af[mi], bfr[ni], acc[mi][ni], 0, 0, 0);
    __builtin_amdgcn_s_barrier();
  }
#undef GEMM_STAGE64

  for (int mi = 0; mi < 2; mi++)
    for (int ni = 0; ni < 4; ni++)
      for (int j = 0; j < 4; j++) {
        const int gm = m0 + wm + mi * 16 + q * 4 + j;
        const int gn = n0 + wn + ni * 16 + r;
        const size_t idx = (size_t)gm * N + gn;
        C[idx] = acc[mi][ni][j] + aux[idx];
      }
}

// ---------------- Flash attention: swapped QK^T, lane-local P, fixed-ref softmax --------
// 8-wave blocks: waves 0-3 own q-tile pr, waves 4-7 own q-tile 63-pr; ONE shared K/V
// staging stream covers both. Bias row lives in LDS (staged once) so the tile body has
// ZERO VMEM -> vmcnt(2) counts only the 2 stage loads/wave and the K/V prefetch finally
// spans the compute (the old in-tile global bias loads forced vmcnt(0) at their use,
// draining the prefetch every tile).
__device__ __forceinline__ void stage_kv8(int w, int lane, int key0,
                                          const __hip_bfloat16* __restrict__ Kg,
                                          const __hip_bfloat16* __restrict__ Vg,
                                          __hip_bfloat16* Ks, __hip_bfloat16* Vs) {
  const int row_in = lane >> 3;        // 0..7
  const int cs = (lane & 7) ^ row_in;  // swizzled 16B-chunk index (XOR by row&7)
  const int row = w * 8 + row_in;      // 0..63 (K: key index, V: dh index)
  gl_lds16(Kg + (size_t)(key0 + row) * QKV_LD + cs * 8, Ks + w * 512 + lane * 8);
  gl_lds16(Vg + (size_t)row * L_SEQ + key0 + cs * 8, Vs + w * 512 + lane * 8);
}

// Swapped QK^T: s = mfma(A=K, B=Q) -> lane (r,q) holds S[key=16hc+4q+j][query=r].
// Fixed-reference log2-domain softmax: p = exp2(s*scale2 + biasLds[key]); per-row
// normalizer cancels in O/ls; bias bounded (+42 max) keeps p in fp32/bf16 range.
// P stays in registers; sigma-permuted V makes each lane's p values its PV A-fragment.
// Rowsum via ones-MFMA (B=1) -> ls[j] = rowsum for query q*4+j, no shuffles.
template <bool CAUSAL>
__device__ __forceinline__ void attn_tile(int key0, int lw0, int r, int q,
                                          const __hip_bfloat16* Ks,
                                          const __hip_bfloat16* Vs,
                                          const float* biasLds,
                                          float scale2,
                                          const bf16x8& qf0, const bf16x8& qf1,
                                          const bf16x8& onesf,
                                          f32x4* o, f32x4& ls) {
  const int r7 = r & 7;
  const f32x4 zz = {0.f, 0.f, 0.f, 0.f};
  f32x4 bias4[4];
#pragma unroll
  for (int hc = 0; hc < 4; hc++)
    bias4[hc] = *(const f32x4*)(biasLds + key0 + hc * 16 + q * 4);  // LDS, broadcast-free
  f32x4 s[4];
  __builtin_amdgcn_s_setprio(1);
#pragma unroll
  for (int hc = 0; hc < 4; hc++) {
    const __hip_bfloat16* kr = Ks + (hc * 16 + r) * 64;
    bf16x8 k0 = *(const bf16x8*)(kr + ((q ^ r7) * 8));
    bf16x8 k1 = *(const bf16x8*)(kr + (((q + 4) ^ r7) * 8));
    f32x4 a = zz;
    a = __builtin_amdgcn_mfma_f32_16x16x32_bf16(k0, qf0, a, 0, 0, 0);
    a = __builtin_amdgcn_mfma_f32_16x16x32_bf16(k1, qf1, a, 0, 0, 0);
    s[hc] = a;
  }
  __builtin_amdgcn_s_setprio(0);
  float p[4][4];
#pragma unroll
  for (int hc = 0; hc < 4; hc++)
#pragma unroll
    for (int j = 0; j < 4; j++) {
      const float v = fmaf(s[hc][j], scale2, bias4[hc][j]);
      float pv = exp2f(v);
      if (CAUSAL) pv = (key0 + hc * 16 + q * 4 + j <= lw0 + r) ? pv : 0.f;
      p[hc][j] = pv;
    }
  // pack P (lane-local) into PV A-fragments; slot order matches sigma-permuted V columns
  bf16x8 pa[2];
#pragma unroll
  for (int kc = 0; kc < 2; kc++) {
    u32x4 pw;
    unsigned w0, w1, w2, w3;
    asm("v_cvt_pk_bf16_f32 %0, %1, %2" : "=v"(w0) : "v"(p[2 * kc][0]), "v"(p[2 * kc][1]));
    asm("v_cvt_pk_bf16_f32 %0, %1, %2" : "=v"(w1) : "v"(p[2 * kc][2]), "v"(p[2 * kc][3]));
    asm("v_cvt_pk_bf16_f32 %0, %1, %2" : "=v"(w2) : "v"(p[2 * kc + 1][0]), "v"(p[2 * kc + 1][1]));
    asm("v_cvt_pk_bf16_f32 %0, %1, %2" : "=v"(w3) : "v"(p[2 * kc + 1][2]), "v"(p[2 * kc + 1][3]));
    pw[0] = w0; pw[1] = w1; pw[2] = w2; pw[3] = w3;
    pa[kc] = *(bf16x8*)&pw;
  }
  __builtin_amdgcn_s_setprio(1);
#pragma unroll
  for (int kc = 0; kc < 2; kc++) {
#pragma unroll
    for (int c = 0; c < 4; c++) {
      const __hip_bfloat16* vr = Vs + (c * 16 + r) * 64 + (((kc * 4 + q) ^ r7) * 8);
      bf16x8 vf = *(const bf16x8*)vr;
      o[c] = __builtin_amdgcn_mfma_f32_16x16x32_bf16(pa[kc], vf, o[c], 0, 0, 0);
    }
    ls = __builtin_amdgcn_mfma_f32_16x16x32_bf16(pa[kc], onesf, ls, 0, 0, 0);
  }
  __builtin_amdgcn_s_setprio(0);
}

// grid: 512 blocks x 512 threads (2 blocks/CU, 16 waves/CU). Block (bh, pr): wave-group A
// (w<4) computes q-tile pr (pr+1 key-tiles), group B computes q-tile 63-pr (64-pr tiles);
// both share the staged K/V stream of length 64-pr tiles -> uniform per-block work (65
// tile-computations) under ANY block->CU assignment.
__global__ __launch_bounds__(512, 2) void attn_kernel(const __hip_bfloat16* __restrict__ qkv,
                                                      const __hip_bfloat16* __restrict__ vt,
                                                      const float* __restrict__ biasH,
                                                      __hip_bfloat16* __restrict__ out) {
  const int blk = blockIdx.x;
  const int bh = blk & 15;
  const int pr = blk >> 4;  // 0..31
  const int b = bh >> 3, h = bh & 7;
  const int tid = threadIdx.x, lane = tid & 63, w = tid >> 6;  // w 0..7
  const int grp = w >> 2, wg = w & 3;
  const int qi = grp ? (63 - pr) : pr;
  const int l0 = qi * 64;
  const int lw0 = l0 + wg * 16;
  const int r = lane & 15, q = lane >> 4;

  __shared__ __align__(16) __hip_bfloat16 Ksm[2][64 * 64];
  __shared__ __align__(16) __hip_bfloat16 Vsm[2][64 * 64];
  __shared__ __align__(16) float biasLds[4096];

  const float LOG2E = 1.4426950408889634f;
  const float scale2 = 0.125f * LOG2E;

  const __hip_bfloat16* Kg = qkv + (size_t)b * L_SEQ * QKV_LD + 512 + h * 64;
  const __hip_bfloat16* Vg = vt + (size_t)bh * 64 * L_SEQ;
  const float* biasHp = biasH + (size_t)bh * L_SEQ;

  // prologue: stage tile 0 K/V + the full 16KB bias row (one-time)
  stage_kv8(w, lane, 0, Kg, Vg, Ksm[0], Vsm[0]);
#pragma unroll
  for (int ii = 0; ii < 2; ii++) {
    const int fo = (w * 2 + ii) * 256;  // 256 floats per gl_lds instruction
    gl_lds16((const __hip_bfloat16*)(biasHp + fo + lane * 4),
             (__hip_bfloat16*)(biasLds + fo + lane * 4));
  }

  bf16x8 qf0, qf1;
  {
    const __hip_bfloat16* qrow = qkv + (size_t)(b * L_SEQ + lw0 + r) * QKV_LD + h * 64 + q * 8;
    qf0 = *(const bf16x8*)qrow;
    qf1 = *(const bf16x8*)(qrow + 32);
  }

  const f32x4 zz = {0.f, 0.f, 0.f, 0.f};
  f32x4 o[4];
  for (int c = 0; c < 4; c++) o[c] = zz;
  f32x4 ls = zz;

  bf16x8 onesf;
  for (int i = 0; i < 8; i++) ((short*)&onesf)[i] = (short)0x3F80;  // bf16 1.0

  const int ntA = pr + 1;        // group-A tiles
  const int ntB = 64 - pr;       // group-B tiles == staging length (ntB > ntA always)
  const int nt = grp ? ntB : ntA;

  for (int t = 0; t < ntB; t++) {
    const int cur = t & 1;
    if (t + 1 < ntB) {
      stage_kv8(w, lane, (t + 1) << 6, Kg, Vg, Ksm[cur ^ 1], Vsm[cur ^ 1]);
      asm volatile("s_waitcnt vmcnt(2)" ::: "memory");  // own tile-t stage (2 loads) retired
    } else {
      asm volatile("s_waitcnt vmcnt(0)" ::: "memory");
    }
    __builtin_amdgcn_s_barrier();  // all waves' tile-t stage complete
    if (t < nt) {                  // wave-uniform
      if (t == nt - 1)
        attn_tile<true>(t << 6, lw0, r, q, Ksm[cur], Vsm[cur], biasLds, scale2, qf0, qf1,
                        onesf, o, ls);
      else
        attn_tile<false>(t << 6, lw0, r, q, Ksm[cur], Vsm[cur], biasLds, scale2, qf0, qf1,
                         onesf, o, ls);
    }
    __builtin_amdgcn_s_barrier();  // reads of buf[cur] done before next stage overwrites
  }

  // ls[j] = rowsum for query q*4+j (same across all lanes r) -> direct normalize
  float invj[4];
  for (int j = 0; j < 4; j++) invj[j] = 1.0f / ls[j];
  for (int c = 0; c < 4; c++)
    for (int j = 0; j < 4; j++) {
      const int rowg = lw0 + q * 4 + j;
      out[(size_t)(b * L_SEQ + rowg) * D_MODEL + h * 64 + c * 16 + r] = f2bf(o[c][j] * invj[j]);
    }
}

// ---------------- Launch ----------------
extern "C" void kernel_launch(void* const* d_in, const int* in_sizes, int n_in,
                              void* d_out, int out_size, void* d_ws, size_t ws_size,
                              hipStream_t stream) {
  const float* x = (const float*)d_in[0];
  const float* ts = (const float*)d_in[1];
  const float* mask = (const float*)d_in[2];
  const float* ln1_g = (const float*)d_in[3];
  const float* ln1_b = (const float*)d_in[4];
  const float* w_qkv = (const float*)d_in[5];
  const float* w_out = (const float*)d_in[6];
  const float* decay = (const float*)d_in[7];
  const float* ln2_g = (const float*)d_in[8];
  const float* ln2_b = (const float*)d_in[9];
  const float* w_ff1 = (const float*)d_in[10];
  const float* w_ff2 = (const float*)d_in[11];

  char* ws = (char*)d_ws;
  // layout (bytes) — total footprint 65,011,712:
  //   [0, 6M)    weights bf16
  //   [6M, 14M)  xn (dead after gemm0) -> vt overlays
  //   [14M, 38M) qkv (dead after attn)
  //   [38M, 46M) attnout -> h
  //   [46M, 62M) x2 (fp32) — biasH (256KB) lives at its HEAD: biasH is dead before
  //              gemm<1> writes x2 (disjoint lifetimes), so no extra ws is used.
  //   ff1out overlays [6M, 38M)
  __hip_bfloat16* wqkv_b = (__hip_bfloat16*)(ws + 0);
  __hip_bfloat16* wout_b = (__hip_bfloat16*)(ws + 1572864);
  __hip_bfloat16* wff1_b = (__hip_bfloat16*)(ws + 2097152);
  __hip_bfloat16* wff2_b = (__hip_bfloat16*)(ws + 4194304);
  __hip_bfloat16* xn = (__hip_bfloat16*)(ws + 6291456);
  __hip_bfloat16* vt = (__hip_bfloat16*)(ws + 6291456);
  __hip_bfloat16* qkv = (__hip_bfloat16*)(ws + 14680064);
  __hip_bfloat16* attnout = (__hip_bfloat16*)(ws + 39845888);
  __hip_bfloat16* h = attnout;
  __hip_bfloat16* ff1out = (__hip_bfloat16*)(ws + 6291456);
  float* x2 = (float*)(ws + 48234496);
  float* biasH = (float*)(ws + 48234496);  // overlays head of x2 (disjoint lifetime)
  float* out = (float*)d_out;

  const int M = 2 * L_SEQ;  // 8192

  cvt4b_kernel<<<dim3(3328), dim3(256), 0, stream>>>(w_qkv, wqkv_b, w_out, wout_b,
                                                     w_ff1, wff1_b, w_ff2, wff2_b,
                                                     ts, mask, decay, biasH);

  ln_kernel<<<dim3(M), dim3(256), 0, stream>>>(x, ln1_g, ln1_b, xn);
  gemm_kernel<0><<<dim3(12, 64), dim3(256), 0, stream>>>(xn, wqkv_b, M, 1536, 512, nullptr, qkv);
  vtrans_kernel<<<dim3(2048), dim3(256), 0, stream>>>(qkv, vt);
  attn_kernel<<<dim3(512), dim3(512), 0, stream>>>(qkv, vt, biasH, attnout);
  gemm_res64_kernel<<<dim3(4, 128), dim3(256), 0, stream>>>(attnout, wout_b, M, 512, 512, x, x2);
  ln_kernel<<<dim3(M), dim3(256), 0, stream>>>(x2, ln2_g, ln2_b, h);
  gemm_kernel<2><<<dim3(16, 64), dim3(256), 0, stream>>>(h, wff1_b, M, 2048, 512, nullptr, ff1out);
  gemm_res64_kernel<<<dim3(4, 128), dim3(256), 0, stream>>>(ff1out, wff2_b, M, 512, 2048, x2, out);
}